// Round 9
// baseline (149.206 us; speedup 1.0000x reference)
//
#include <hip/hip_runtime.h>
#include <hip/hip_bf16.h>
#include <math.h>

#define BATCHN  16
#define SEQ     1024
#define DMODEL  256
#define DSTATE  128
#define HEADDIM 64
#define DINNER  512
#define NHEADS  8
#define CONVDIM 768
#define DINPROJ 1288
#define ZXLD    1280
#define KCONV   4
#define NCHUNK  16
#define LCHUNK  64
#define EPSV    1e-5f
#define ROWS    (BATCHN*SEQ)

typedef __attribute__((ext_vector_type(8))) __bf16 bf16x8;
typedef __attribute__((ext_vector_type(4))) float  f32x4;

__device__ inline ushort f2bf(float f) {
    union { float f; uint32_t u; } v; v.f = f;
    uint32_t r = v.u + 0x7fff + ((v.u >> 16) & 1);
    return (ushort)(r >> 16);
}
__device__ inline float bf2f(ushort u) {
    union { uint32_t u; float f; } v; v.u = ((uint32_t)u) << 16;
    return v.f;
}

// ------------------- merged W_in/W_out transpose + cast to bf16 (448 blocks)
__global__ __launch_bounds__(256) void transpose_cast2_k(const float* __restrict__ W_in,
                                                         const float* __restrict__ W_out,
                                                         ushort* __restrict__ WtA,
                                                         ushort* __restrict__ WtB) {
    __shared__ float Ts[32][33];
    int bid = blockIdx.x;
    const float* src; ushort* dst; int K, ldsrc, nx;
    if (bid < 320) { src = W_in;  dst = WtA; K = DMODEL; ldsrc = DINPROJ; nx = 40; }
    else { bid -= 320; src = W_out; dst = WtB; K = DINNER; ldsrc = DMODEL; nx = 8; }
    const int n0 = (bid % nx) * 32, k0 = (bid / nx) * 32;
    const int tx = threadIdx.x & 31, ty = threadIdx.x >> 5;
    #pragma unroll
    for (int j = 0; j < 4; ++j) {
        int kl = ty * 4 + j;
        Ts[kl][tx] = src[(size_t)(k0 + kl) * ldsrc + n0 + tx];
    }
    __syncthreads();
    #pragma unroll
    for (int j = 0; j < 4; ++j) {
        int nl = ty * 4 + j;
        dst[(size_t)(n0 + nl) * K + k0 + tx] = f2bf(Ts[tx][nl]);
    }
}

// -------------- dt GEMV (exact f32) + u -> bf16 cast, one u read total
__global__ __launch_bounds__(256) void dt_cast_k(const float* __restrict__ u,
                                                 const float* __restrict__ W_in,
                                                 const float* __restrict__ dt_bias,
                                                 const float* __restrict__ A_log,
                                                 ushort* __restrict__ ubf,
                                                 float* __restrict__ dtb,
                                                 float* __restrict__ adtb) {
    __shared__ float Uld[32][264];
    __shared__ float Ws[DMODEL][NHEADS];
    const int tid = threadIdx.x;
    #pragma unroll
    for (int j = 0; j < 8; ++j) {
        int idx = tid + j * 256;
        Ws[idx >> 3][idx & 7] = W_in[(size_t)(idx >> 3) * DINPROJ + 1280 + (idx & 7)];
    }
    const int row0 = blockIdx.x * 32;
    #pragma unroll
    for (int v = 0; v < 8; ++v) {
        int e = v * 1024 + tid * 4;
        int r = e >> 8, cc = e & 255;
        float4 x = *(const float4*)&u[(size_t)(row0 + r) * DMODEL + cc];
        *(float4*)&Uld[r][cc] = x;
        ushort t4[4];
        t4[0]=f2bf(x.x); t4[1]=f2bf(x.y); t4[2]=f2bf(x.z); t4[3]=f2bf(x.w);
        *(ushort4*)&ubf[(size_t)(row0 + r) * DMODEL + cc] = *(ushort4*)t4;
    }
    __syncthreads();
    const int row = tid >> 3, h = tid & 7;
    float acc = 0.f;
    #pragma unroll 8
    for (int k = 0; k < DMODEL; k += 4) {
        float4 uv = *(const float4*)&Uld[row][k];
        acc += uv.x * Ws[k][h] + uv.y * Ws[k+1][h] + uv.z * Ws[k+2][h] + uv.w * Ws[k+3][h];
    }
    float v = acc + dt_bias[h];
    float dt = (v > 20.f) ? v : log1pf(__expf(v));
    dtb [(size_t)(row0 + row) * NHEADS + h] = dt;
    adtb[(size_t)(row0 + row) * NHEADS + h] = dt * (-__expf(A_log[h]));
}

// ------------------------------------------------------- bf16 MFMA GEMM
#define LDSW 72
template<typename CT>
__global__ __launch_bounds__(256) void gemm_bf16(const ushort* __restrict__ A,
                                                 const ushort* __restrict__ Bt,
                                                 CT* __restrict__ C,
                                                 int M, int N, int K, int nx) {
    __shared__ ushort As[128 * LDSW];
    __shared__ ushort Bs[128 * LDSW];
    const int tid  = threadIdx.x;
    const int nwg  = gridDim.x;
    const int work = (blockIdx.x & 7) * (nwg >> 3) + (blockIdx.x >> 3);
    const int m0 = (work / nx) * 128, n0 = (work % nx) * 128;
    const int wid = tid >> 6, lane = tid & 63;
    const int wr = wid >> 1, wc = wid & 1;
    const int r = tid >> 1, kq = tid & 1;
    const int fr = lane & 15, kc = lane >> 4;

    f32x4 acc[4][4];
    #pragma unroll
    for (int i = 0; i < 4; ++i)
        #pragma unroll
        for (int j = 0; j < 4; ++j) acc[i][j] = (f32x4)0.f;

    for (int kt = 0; kt < K; kt += 64) {
        const ushort* ap = &A [(size_t)(m0 + r) * K + kt + kq * 32];
        const ushort* bp = &Bt[(size_t)(n0 + r) * K + kt + kq * 32];
        #pragma unroll
        for (int v = 0; v < 4; ++v) {
            *(uint4*)&As[r * LDSW + kq * 32 + v * 8] = *(const uint4*)(ap + v * 8);
            *(uint4*)&Bs[r * LDSW + kq * 32 + v * 8] = *(const uint4*)(bp + v * 8);
        }
        __syncthreads();
        #pragma unroll
        for (int kk = 0; kk < 2; ++kk) {
            bf16x8 af[4], bfv[4];
            #pragma unroll
            for (int i = 0; i < 4; ++i) {
                af[i]  = *(const bf16x8*)&As[(wr * 64 + i * 16 + fr) * LDSW + kk * 32 + kc * 8];
                bfv[i] = *(const bf16x8*)&Bs[(wc * 64 + i * 16 + fr) * LDSW + kk * 32 + kc * 8];
            }
            #pragma unroll
            for (int i = 0; i < 4; ++i)
                #pragma unroll
                for (int j = 0; j < 4; ++j)
                    acc[i][j] = __builtin_amdgcn_mfma_f32_16x16x32_bf16(af[i], bfv[j], acc[i][j], 0, 0, 0);
        }
        __syncthreads();
    }
    #pragma unroll
    for (int i = 0; i < 4; ++i)
        #pragma unroll
        for (int j = 0; j < 4; ++j)
            #pragma unroll
            for (int q = 0; q < 4; ++q) {
                int rr = m0 + wr * 64 + i * 16 + (lane >> 4) * 4 + q;
                int cc = n0 + wc * 64 + j * 16 + (lane & 15);
                if constexpr (sizeof(CT) == 4) C[(size_t)rr * N + cc] = acc[i][j][q];
                else                           C[(size_t)rr * N + cc] = f2bf(acc[i][j][q]);
            }
}

// ------------------- depthwise conv + SiLU: LDS weights, 4 t-steps/thread
__global__ __launch_bounds__(256) void conv_silu_k(const ushort* __restrict__ zx,
                                                   const float* __restrict__ cw,
                                                   const float* __restrict__ cb,
                                                   ushort* __restrict__ out) {
    __shared__ float cws[KCONV][CONVDIM];
    __shared__ float cbs[CONVDIM];
    const int tid = threadIdx.x;
    #pragma unroll
    for (int it = 0; it < 3; ++it) {
        int i = tid + it * 256;
        cbs[i] = cb[i];
        #pragma unroll
        for (int k = 0; k < KCONV; ++k) cws[k][i] = cw[i * KCONV + k];
    }
    __syncthreads();

    const int idx = blockIdx.x * 256 + tid;
    const int cg = idx % 96, btq = idx / 96;
    const int c0 = cg * 8;
    const int bt0 = btq * 4;
    const int t0 = bt0 & (SEQ - 1);

    float wv[KCONV][8], bias[8];
    #pragma unroll
    for (int j = 0; j < 8; ++j) bias[j] = cbs[c0 + j];
    #pragma unroll
    for (int k = 0; k < KCONV; ++k) {
        float4 a = *(const float4*)&cws[k][c0];
        float4 b = *(const float4*)&cws[k][c0 + 4];
        wv[k][0] = a.x; wv[k][1] = a.y; wv[k][2] = a.z; wv[k][3] = a.w;
        wv[k][4] = b.x; wv[k][5] = b.y; wv[k][6] = b.z; wv[k][7] = b.w;
    }
    float xr[7][8];
    #pragma unroll
    for (int r = 0; r < 7; ++r) {
        int tt = t0 - 3 + r;
        if (tt >= 0) {
            uint4 v = *(const uint4*)&zx[(size_t)(bt0 - 3 + r) * ZXLD + DINNER + c0];
            const ushort* pv = (const ushort*)&v;
            #pragma unroll
            for (int j = 0; j < 8; ++j) xr[r][j] = bf2f(pv[j]);
        } else {
            #pragma unroll
            for (int j = 0; j < 8; ++j) xr[r][j] = 0.f;
        }
    }
    #pragma unroll
    for (int dt = 0; dt < 4; ++dt) {
        float acc[8];
        #pragma unroll
        for (int j = 0; j < 8; ++j) acc[j] = bias[j];
        #pragma unroll
        for (int k = 0; k < KCONV; ++k)
            #pragma unroll
            for (int j = 0; j < 8; ++j) acc[j] += xr[dt + k][j] * wv[k][j];
        ushort res[8];
        #pragma unroll
        for (int j = 0; j < 8; ++j)
            res[j] = f2bf(acc[j] / (1.f + __expf(-acc[j])));
        *(uint4*)&out[(size_t)(bt0 + dt) * CONVDIM + c0] = *(uint4*)res;
    }
}

// ---------------- fused SSD: Y_diag + inter-chunk scan + Y_off, one kernel
// grid (2 p-half, 8 h, 16 b) = 256 blocks (1/CU), 512 threads (8 waves).
// S_pref[32][128] lives in registers (2 f32x4/thread), bf16 copy in LDS for
// the Y_off MFMA of the next chunk.
#define SLDA 136
#define SLDB 72
__global__ __launch_bounds__(512) void ssd_fused_k(const ushort* __restrict__ xbc,
                                                   const float* __restrict__ dtb,
                                                   const float* __restrict__ adtb,
                                                   const float* __restrict__ Dp,
                                                   ushort* __restrict__ ybuf) {
    const int ph = blockIdx.x, h = blockIdx.y, b = blockIdx.z;
    const int p0 = ph * 32;
    const int tid = threadIdx.x;
    const int lane = tid & 63, w = tid >> 6;
    const int fr = lane & 15, kc = lane >> 4;

    __shared__ ushort Bsh[64][SLDA];
    __shared__ ushort Csh[64][SLDA];
    __shared__ ushort Btr[128][SLDB];
    __shared__ ushort Ps [64][SLDB];
    __shared__ ushort Xt [32][SLDB];
    __shared__ ushort Xdt[32][SLDB];
    __shared__ ushort Spl[32][SLDA];   // S_pref^T (p-local rows, n cols), bf16
    __shared__ float acs_s[64], dts_s[64], decs_s[64];

    const float Dh = Dp[h];
    // zero Spl (32x16 uint4 grains, one per thread)
    { int p = tid >> 4, ng = tid & 15;
      uint4 z; z.x = z.y = z.z = z.w = 0u;
      *(uint4*)&Spl[p][ng * 8] = z; }
    // S_pref register frags: wave w -> rows mt*16.., col-frags nt0,nt0+1
    const int mt = w & 1, nt0 = (w >> 1) * 2;
    f32x4 Sp[2];
    Sp[0] = (f32x4)0.f; Sp[1] = (f32x4)0.f;
    __syncthreads();

    for (int c = 0; c < NCHUNK; ++c) {
        const int row0 = b * SEQ + c * LCHUNK;
        // ---- phase 1: cumsum (wave 0) + stage B,C,Btr (all)
        if (w == 0) {
            float v = adtb[(size_t)(row0 + lane) * NHEADS + h];
            #pragma unroll
            for (int off = 1; off < 64; off <<= 1) {
                float t = __shfl_up(v, off);
                if (lane >= off) v += t;
            }
            acs_s[lane] = v;
            float tot = __shfl(v, 63);
            decs_s[lane] = __expf(tot - v);
            dts_s[lane] = dtb[(size_t)(row0 + lane) * NHEADS + h];
        }
        #pragma unroll
        for (int it = 0; it < 2; ++it) {
            int idx = tid + it * 512;        // 1024 grains: l(64) x ng(16)
            int l = idx >> 4, ng = idx & 15;
            const ushort* rp = &xbc[(size_t)(row0 + l) * CONVDIM + DINNER];
            uint4 vb = *(const uint4*)(rp + ng * 8);
            *(uint4*)&Bsh[l][ng * 8] = vb;
            uint4 vc = *(const uint4*)(rp + DSTATE + ng * 8);
            *(uint4*)&Csh[l][ng * 8] = vc;
            const ushort* pv = (const ushort*)&vb;
            #pragma unroll
            for (int j = 0; j < 8; ++j) Btr[ng * 8 + j][l] = pv[j];
        }
        __syncthreads();   // sync1

        // ---- G = C.B^T : wave w -> rows gi*16, cols (gj0+jj)*16
        const int gi = w >> 1, gj0 = (w & 1) * 2;
        f32x4 accG[2];
        accG[0] = (f32x4)0.f; accG[1] = (f32x4)0.f;
        #pragma unroll
        for (int kt = 0; kt < 4; ++kt) {
            bf16x8 af = *(const bf16x8*)&Csh[gi*16 + fr][kt*32 + kc*8];
            #pragma unroll
            for (int jj = 0; jj < 2; ++jj) {
                bf16x8 bfv = *(const bf16x8*)&Bsh[(gj0+jj)*16 + fr][kt*32 + kc*8];
                accG[jj] = __builtin_amdgcn_mfma_f32_16x16x32_bf16(af, bfv, accG[jj], 0, 0, 0);
            }
        }
        // ---- P build (decay mask + D/dt on diagonal)
        #pragma unroll
        for (int jj = 0; jj < 2; ++jj)
            #pragma unroll
            for (int q = 0; q < 4; ++q) {
                int l = gi*16 + (lane >> 4)*4 + q;
                int s = (gj0+jj)*16 + fr;
                float v = 0.f;
                if (s < l)       v = accG[jj][q] * __expf(acs_s[l] - acs_s[s]);
                else if (s == l) v = accG[jj][q] + Dh / dts_s[l];
                Ps[l][s] = f2bf(v);
            }
        // ---- Xt/Xdt build (first 256 threads)
        if (tid < 256) {
            int l = tid >> 2, gg = tid & 3;
            uint4 xv4 = *(const uint4*)&xbc[(size_t)(row0 + l) * CONVDIM
                                            + h * HEADDIM + p0 + gg * 8];
            const ushort* pv = (const ushort*)&xv4;
            float dt_l = dts_s[l], dec_l = decs_s[l];
            #pragma unroll
            for (int j = 0; j < 8; ++j) {
                float xv = bf2f(pv[j]) * dt_l;
                Xt [gg*8 + j][l] = f2bf(xv);
                Xdt[gg*8 + j][l] = f2bf(xv * dec_l);
            }
        }
        // ---- accO = C @ Spl^T (prefix of chunks < c) : wave w -> (yi,yj)
        const int yi = w >> 1, yj = w & 1;
        f32x4 accO = (f32x4)0.f;
        #pragma unroll
        for (int kt = 0; kt < 4; ++kt) {
            bf16x8 af  = *(const bf16x8*)&Csh[yi*16 + fr][kt*32 + kc*8];
            bf16x8 bfv = *(const bf16x8*)&Spl[yj*16 + fr][kt*32 + kc*8];
            accO = __builtin_amdgcn_mfma_f32_16x16x32_bf16(af, bfv, accO, 0, 0, 0);
        }
        __syncthreads();   // sync2 (Ps/Xt ready; all Spl reads done)

        // ---- accD = P @ Xt^T, write Y = accD + accO*exp(acs)
        f32x4 accD = (f32x4)0.f;
        #pragma unroll
        for (int kt = 0; kt < 2; ++kt) {
            bf16x8 af  = *(const bf16x8*)&Ps[yi*16 + fr][kt*32 + kc*8];
            bf16x8 bfv = *(const bf16x8*)&Xt[yj*16 + fr][kt*32 + kc*8];
            accD = __builtin_amdgcn_mfma_f32_16x16x32_bf16(af, bfv, accD, 0, 0, 0);
        }
        #pragma unroll
        for (int q = 0; q < 4; ++q) {
            int l = yi*16 + (lane >> 4)*4 + q;
            float ea = __expf(acs_s[l]);
            ybuf[(size_t)(row0 + l) * DINNER + h * HEADDIM + p0 + yj*16 + fr]
                = f2bf(accD[q] + accO[q] * ea);
        }
        // ---- S_c = Xdt @ Btr^T; scan update; publish Spl
        f32x4 accS[2];
        accS[0] = (f32x4)0.f; accS[1] = (f32x4)0.f;
        #pragma unroll
        for (int kt = 0; kt < 2; ++kt) {
            bf16x8 af = *(const bf16x8*)&Xdt[mt*16 + fr][kt*32 + kc*8];
            #pragma unroll
            for (int jt = 0; jt < 2; ++jt) {
                bf16x8 bfv = *(const bf16x8*)&Btr[(nt0+jt)*16 + fr][kt*32 + kc*8];
                accS[jt] = __builtin_amdgcn_mfma_f32_16x16x32_bf16(af, bfv, accS[jt], 0, 0, 0);
            }
        }
        const float decC = __expf(acs_s[63]);
        #pragma unroll
        for (int jt = 0; jt < 2; ++jt)
            #pragma unroll
            for (int q = 0; q < 4; ++q) {
                Sp[jt][q] = decC * Sp[jt][q] + accS[jt][q];
                int p = mt*16 + (lane >> 4)*4 + q;
                int n = (nt0+jt)*16 + fr;
                Spl[p][n] = f2bf(Sp[jt][q]);
            }
        __syncthreads();   // sync3
    }
}

// ----------------------------------------- gate (silu(z)) + RMSNorm -> bf16 g
__global__ __launch_bounds__(256) void gate_norm_k(const ushort* __restrict__ ybuf,
                                                   const ushort* __restrict__ zx,
                                                   const float* __restrict__ nw,
                                                   ushort* __restrict__ gbuf) {
    const int row  = blockIdx.x * 4 + (threadIdx.x >> 6);
    const int lane = threadIdx.x & 63;
    uint4 yv = *(const uint4*)&ybuf[(size_t)row * DINNER + lane * 8];
    uint4 zv = *(const uint4*)&zx[(size_t)row * ZXLD + lane * 8];
    const ushort* py = (const ushort*)&yv;
    const ushort* pz = (const ushort*)&zv;
    float g[8], ss = 0.f;
    #pragma unroll
    for (int j = 0; j < 8; ++j) {
        float y = bf2f(py[j]);
        float z = bf2f(pz[j]);
        float sz = z / (1.f + __expf(-z));
        g[j] = y * sz;
        ss += g[j] * g[j];
    }
    #pragma unroll
    for (int off = 32; off; off >>= 1) ss += __shfl_xor(ss, off);
    float r = rsqrtf(ss / (float)DINNER + EPSV);
    ushort res[8];
    #pragma unroll
    for (int j = 0; j < 8; ++j) res[j] = f2bf(g[j] * r * nw[lane * 8 + j]);
    *(uint4*)&gbuf[(size_t)row * DINNER + lane * 8] = *(uint4*)res;
}

// ---------------------------------------------------------------- launch
extern "C" void kernel_launch(void* const* d_in, const int* in_sizes, int n_in,
                              void* d_out, int out_size, void* d_ws, size_t ws_size,
                              hipStream_t stream) {
    const float* u       = (const float*)d_in[0];
    const float* W_in    = (const float*)d_in[1];
    const float* conv_w  = (const float*)d_in[2];
    const float* conv_b  = (const float*)d_in[3];
    const float* dt_bias = (const float*)d_in[4];
    const float* A_log   = (const float*)d_in[5];
    const float* Dp      = (const float*)d_in[6];
    const float* norm_w  = (const float*)d_in[7];
    const float* W_out   = (const float*)d_in[8];
    float* out = (float*)d_out;

    char* p = (char*)d_ws;
    ushort* zx       = (ushort*)p; p += (size_t)ROWS * ZXLD * sizeof(ushort);
    ushort* ybuf     = (ushort*)p; p += (size_t)ROWS * DINNER * sizeof(ushort);
    ushort* gbuf     = (ushort*)p; p += (size_t)ROWS * DINNER * sizeof(ushort);
    ushort* xbc      = (ushort*)p; p += (size_t)ROWS * CONVDIM * sizeof(ushort);
    ushort* ubf      = (ushort*)p; p += (size_t)ROWS * DMODEL * sizeof(ushort);
    float*  dtb      = (float*)p;  p += (size_t)ROWS * NHEADS  * sizeof(float);
    float*  adtb     = (float*)p;  p += (size_t)ROWS * NHEADS  * sizeof(float);
    ushort* WtA      = (ushort*)p; p += (size_t)ZXLD * DMODEL * sizeof(ushort);
    ushort* WtB      = (ushort*)p; p += (size_t)DMODEL * DINNER * sizeof(ushort);

    // 1. dt GEMV (exact f32) + u->bf16 cast
    dt_cast_k<<<ROWS/32, 256, 0, stream>>>(u, W_in, dt_bias, A_log, ubf, dtb, adtb);
    // 2. weight transposes
    transpose_cast2_k<<<448, 256, 0, stream>>>(W_in, W_out, WtA, WtB);
    // 3. in-proj -> bf16 zx
    gemm_bf16<ushort><<<(ZXLD/128)*(ROWS/128), 256, 0, stream>>>(
        ubf, WtA, zx, ROWS, ZXLD, DMODEL, ZXLD/128);
    // 4. depthwise conv + silu
    conv_silu_k<<<(ROWS/4)*96/256, 256, 0, stream>>>(zx, conv_w, conv_b, xbc);
    // 5. fused SSD (diag + scan + off-diag)
    ssd_fused_k<<<dim3(2, NHEADS, BATCHN), 512, 0, stream>>>(
        xbc, dtb, adtb, Dp, ybuf);
    // 6. gate + RMSNorm
    gate_norm_k<<<ROWS/4, 256, 0, stream>>>(ybuf, zx, norm_w, gbuf);
    // 7. out-proj
    gemm_bf16<float><<<(DMODEL/128)*(ROWS/128), 256, 0, stream>>>(
        gbuf, WtB, out, ROWS, DMODEL, DINNER, DMODEL/128);
}

// Round 10
// 141.976 us; speedup vs baseline: 1.0509x; 1.0509x over previous
//
#include <hip/hip_runtime.h>
#include <hip/hip_bf16.h>
#include <math.h>

#define BATCHN  16
#define SEQ     1024
#define DMODEL  256
#define DSTATE  128
#define HEADDIM 64
#define DINNER  512
#define NHEADS  8
#define CONVDIM 768
#define DINPROJ 1288
#define ZXLD    1280
#define KCONV   4
#define NCHUNK  16
#define LCHUNK  64
#define EPSV    1e-5f
#define ROWS    (BATCHN*SEQ)

typedef __attribute__((ext_vector_type(8))) __bf16 bf16x8;
typedef __attribute__((ext_vector_type(4))) float  f32x4;

__device__ inline ushort f2bf(float f) {
    union { float f; uint32_t u; } v; v.f = f;
    uint32_t r = v.u + 0x7fff + ((v.u >> 16) & 1);
    return (ushort)(r >> 16);
}
__device__ inline float bf2f(ushort u) {
    union { uint32_t u; float f; } v; v.u = ((uint32_t)u) << 16;
    return v.f;
}

// ------------------- merged W_in/W_out transpose + cast to bf16 (448 blocks)
__global__ __launch_bounds__(256) void transpose_cast2_k(const float* __restrict__ W_in,
                                                         const float* __restrict__ W_out,
                                                         ushort* __restrict__ WtA,
                                                         ushort* __restrict__ WtB) {
    __shared__ float Ts[32][33];
    int bid = blockIdx.x;
    const float* src; ushort* dst; int K, ldsrc, nx;
    if (bid < 320) { src = W_in;  dst = WtA; K = DMODEL; ldsrc = DINPROJ; nx = 40; }
    else { bid -= 320; src = W_out; dst = WtB; K = DINNER; ldsrc = DMODEL; nx = 8; }
    const int n0 = (bid % nx) * 32, k0 = (bid / nx) * 32;
    const int tx = threadIdx.x & 31, ty = threadIdx.x >> 5;
    #pragma unroll
    for (int j = 0; j < 4; ++j) {
        int kl = ty * 4 + j;
        Ts[kl][tx] = src[(size_t)(k0 + kl) * ldsrc + n0 + tx];
    }
    __syncthreads();
    #pragma unroll
    for (int j = 0; j < 4; ++j) {
        int nl = ty * 4 + j;
        dst[(size_t)(n0 + nl) * K + k0 + tx] = f2bf(Ts[tx][nl]);
    }
}

// -------------- dt GEMV (exact f32) + u -> bf16 cast, one u read total
__global__ __launch_bounds__(256) void dt_cast_k(const float* __restrict__ u,
                                                 const float* __restrict__ W_in,
                                                 const float* __restrict__ dt_bias,
                                                 const float* __restrict__ A_log,
                                                 ushort* __restrict__ ubf,
                                                 float* __restrict__ dtb,
                                                 float* __restrict__ adtb) {
    __shared__ float Uld[32][264];
    __shared__ float Ws[DMODEL][NHEADS];
    const int tid = threadIdx.x;
    #pragma unroll
    for (int j = 0; j < 8; ++j) {
        int idx = tid + j * 256;
        Ws[idx >> 3][idx & 7] = W_in[(size_t)(idx >> 3) * DINPROJ + 1280 + (idx & 7)];
    }
    const int row0 = blockIdx.x * 32;
    #pragma unroll
    for (int v = 0; v < 8; ++v) {
        int e = v * 1024 + tid * 4;
        int r = e >> 8, cc = e & 255;
        float4 x = *(const float4*)&u[(size_t)(row0 + r) * DMODEL + cc];
        *(float4*)&Uld[r][cc] = x;
        ushort t4[4];
        t4[0]=f2bf(x.x); t4[1]=f2bf(x.y); t4[2]=f2bf(x.z); t4[3]=f2bf(x.w);
        *(ushort4*)&ubf[(size_t)(row0 + r) * DMODEL + cc] = *(ushort4*)t4;
    }
    __syncthreads();
    const int row = tid >> 3, h = tid & 7;
    float acc = 0.f;
    #pragma unroll 8
    for (int k = 0; k < DMODEL; k += 4) {
        float4 uv = *(const float4*)&Uld[row][k];
        acc += uv.x * Ws[k][h] + uv.y * Ws[k+1][h] + uv.z * Ws[k+2][h] + uv.w * Ws[k+3][h];
    }
    float v = acc + dt_bias[h];
    float dt = (v > 20.f) ? v : log1pf(__expf(v));
    dtb [(size_t)(row0 + row) * NHEADS + h] = dt;
    adtb[(size_t)(row0 + row) * NHEADS + h] = dt * (-__expf(A_log[h]));
}

// --------------- bf16 MFMA GEMM; FCONV: fused depthwise conv+SiLU epilogue
#define LDSW 72
#define TILEW 136
template<typename CT, bool FCONV>
__global__ __launch_bounds__(256) void gemm_bf16(const ushort* __restrict__ A,
                                                 const ushort* __restrict__ Bt,
                                                 CT* __restrict__ C,
                                                 int M, int N, int K, int nx,
                                                 const float* __restrict__ cw,
                                                 const float* __restrict__ cb,
                                                 ushort* __restrict__ xbc) {
    __shared__ ushort LB[2 * 128 * LDSW];     // As | Bs ; reused as conv Tile
    __shared__ float cwsl[128][4];
    __shared__ float cbl[128];
    ushort* As = LB;
    ushort* Bs = LB + 128 * LDSW;
    const int tid  = threadIdx.x;
    const int nwg  = gridDim.x;
    const int work = (blockIdx.x & 7) * (nwg >> 3) + (blockIdx.x >> 3);
    const int m0 = (work / nx) * 128, n0 = (work % nx) * 128;
    const int wid = tid >> 6, lane = tid & 63;
    const int wr = wid >> 1, wc = wid & 1;
    const int r = tid >> 1, kq = tid & 1;
    const int fr = lane & 15, kc = lane >> 4;
    const bool doconv = FCONV && (n0 >= DINNER);

    if constexpr (FCONV) {
        if (doconv) {   // stage this block's 128-channel conv weights (coalesced)
            int cbase = n0 - DINNER;
            if (tid < 128) cbl[tid] = cb[cbase + tid];
            #pragma unroll
            for (int s = 0; s < 2; ++s) {
                int flat = tid + s * 256;
                cwsl[flat >> 2][flat & 3] = cw[cbase * 4 + flat];
            }
        }
    }

    f32x4 acc[4][4];
    #pragma unroll
    for (int i = 0; i < 4; ++i)
        #pragma unroll
        for (int j = 0; j < 4; ++j) acc[i][j] = (f32x4)0.f;

    for (int kt = 0; kt < K; kt += 64) {
        const ushort* ap = &A [(size_t)(m0 + r) * K + kt + kq * 32];
        const ushort* bp = &Bt[(size_t)(n0 + r) * K + kt + kq * 32];
        #pragma unroll
        for (int v = 0; v < 4; ++v) {
            *(uint4*)&As[r * LDSW + kq * 32 + v * 8] = *(const uint4*)(ap + v * 8);
            *(uint4*)&Bs[r * LDSW + kq * 32 + v * 8] = *(const uint4*)(bp + v * 8);
        }
        __syncthreads();
        #pragma unroll
        for (int kk = 0; kk < 2; ++kk) {
            bf16x8 af[4], bfv[4];
            #pragma unroll
            for (int i = 0; i < 4; ++i) {
                af[i]  = *(const bf16x8*)&As[(wr * 64 + i * 16 + fr) * LDSW + kk * 32 + kc * 8];
                bfv[i] = *(const bf16x8*)&Bs[(wc * 64 + i * 16 + fr) * LDSW + kk * 32 + kc * 8];
            }
            #pragma unroll
            for (int i = 0; i < 4; ++i)
                #pragma unroll
                for (int j = 0; j < 4; ++j)
                    acc[i][j] = __builtin_amdgcn_mfma_f32_16x16x32_bf16(af[i], bfv[j], acc[i][j], 0, 0, 0);
        }
        __syncthreads();    // after last iter: As/Bs dead -> Tile overlay safe
    }
    ushort (*Tile)[TILEW] = (ushort (*)[TILEW])LB;
    #pragma unroll
    for (int i = 0; i < 4; ++i)
        #pragma unroll
        for (int j = 0; j < 4; ++j)
            #pragma unroll
            for (int q = 0; q < 4; ++q) {
                int rl = wr * 64 + i * 16 + (lane >> 4) * 4 + q;
                int cl = wc * 64 + j * 16 + (lane & 15);
                if constexpr (sizeof(CT) == 4) C[(size_t)(m0 + rl) * N + n0 + cl] = acc[i][j][q];
                else {
                    ushort bv = f2bf(acc[i][j][q]);
                    C[(size_t)(m0 + rl) * N + n0 + cl] = bv;
                    if (doconv) Tile[rl][cl] = bv;
                }
            }
    if constexpr (FCONV) {
        if (!doconv) return;
        __syncthreads();
        // conv+SiLU from Tile: thread = (8 channels, 8 rows); rows 0-2 -> fixup
        const int cg = tid & 15, rg = tid >> 4;
        const int c0l = cg * 8;
        float wk[KCONV][8], bias[8];
        #pragma unroll
        for (int k = 0; k < KCONV; ++k)
            #pragma unroll
            for (int j = 0; j < 8; ++j) wk[k][j] = cwsl[c0l + j][k];
        #pragma unroll
        for (int j = 0; j < 8; ++j) bias[j] = cbl[c0l + j];
        const int start = (rg == 0) ? 3 : rg * 8;
        float win[3][8];
        #pragma unroll
        for (int s = 0; s < 3; ++s) {
            uint4 v = *(const uint4*)&Tile[start - 3 + s][c0l];
            const ushort* pv = (const ushort*)&v;
            #pragma unroll
            for (int j = 0; j < 8; ++j) win[s][j] = bf2f(pv[j]);
        }
        for (int rr = start; rr < rg * 8 + 8; ++rr) {
            uint4 v = *(const uint4*)&Tile[rr][c0l];
            const ushort* pv = (const ushort*)&v;
            float cur[8], a8[8];
            #pragma unroll
            for (int j = 0; j < 8; ++j) {
                cur[j] = bf2f(pv[j]);
                a8[j] = bias[j] + wk[0][j]*win[0][j] + wk[1][j]*win[1][j]
                                + wk[2][j]*win[2][j] + wk[3][j]*cur[j];
            }
            #pragma unroll
            for (int j = 0; j < 8; ++j) {
                win[0][j] = win[1][j]; win[1][j] = win[2][j]; win[2][j] = cur[j];
            }
            ushort res[8];
            #pragma unroll
            for (int j = 0; j < 8; ++j)
                res[j] = f2bf(a8[j] / (1.f + __expf(-a8[j])));
            *(uint4*)&xbc[(size_t)(m0 + rr) * CONVDIM + (n0 - DINNER) + c0l] = *(uint4*)res;
        }
    }
}

// ---------------- conv boundary fixup: rows 0..2 of each 128-row tile
__global__ __launch_bounds__(256) void conv_fix_k(const ushort* __restrict__ zx,
                                                  const float* __restrict__ cw,
                                                  const float* __restrict__ cb,
                                                  ushort* __restrict__ xbc) {
    __shared__ float cws[KCONV][CONVDIM];
    __shared__ float cbs[CONVDIM];
    const int tid = threadIdx.x;
    #pragma unroll
    for (int it = 0; it < 3; ++it) {
        int i = tid + it * 256;
        cbs[i] = cb[i];
        #pragma unroll
        for (int k = 0; k < KCONV; ++k) cws[k][i] = cw[i * KCONV + k];
    }
    __syncthreads();
    const int m0 = blockIdx.x * 128;
    for (int it = tid; it < 288; it += 256) {   // 3 rows x 96 ch-groups
        int l = it / 96, cg = it % 96;
        int c0 = cg * 8;
        int bt = m0 + l;
        int t = bt & (SEQ - 1);
        float a8[8];
        #pragma unroll
        for (int j = 0; j < 8; ++j) a8[j] = cbs[c0 + j];
        #pragma unroll
        for (int k = 0; k < KCONV; ++k) {
            int tt = t - 3 + k;
            if (tt < 0) continue;
            uint4 v = *(const uint4*)&zx[(size_t)(bt - 3 + k) * ZXLD + DINNER + c0];
            const ushort* pv = (const ushort*)&v;
            #pragma unroll
            for (int j = 0; j < 8; ++j) a8[j] += bf2f(pv[j]) * cws[k][c0 + j];
        }
        ushort res[8];
        #pragma unroll
        for (int j = 0; j < 8; ++j)
            res[j] = f2bf(a8[j] / (1.f + __expf(-a8[j])));
        *(uint4*)&xbc[(size_t)bt * CONVDIM + c0] = *(uint4*)res;
    }
}

// -------------------------------------------------- SSD MFMA kernel
#define SLDA 136
#define SLDB 72
__global__ __launch_bounds__(256) void ssd_mfma_k(const ushort* __restrict__ xbc,
                                                  const float* __restrict__ dtb,
                                                  const float* __restrict__ adtb,
                                                  const float* __restrict__ Dp,
                                                  ushort* __restrict__ ybuf,
                                                  ushort* __restrict__ states,
                                                  float* __restrict__ acsbuf,
                                                  float* __restrict__ chunksum) {
    const int hgrp = blockIdx.x, c = blockIdx.y, b = blockIdx.z;
    const int row0 = b * SEQ + c * LCHUNK;
    const int tid = threadIdx.x;
    const int lane = tid & 63, w = tid >> 6;
    const int fr = lane & 15, kc = lane >> 4;

    __shared__ union {
        struct { ushort Bs[64][SLDA]; ushort Cs[64][SLDA]; } p1;
        struct { ushort Ps[64][SLDB]; ushort Xt[64][SLDB]; ushort Xdt[64][SLDB]; } p2;
    } U;
    __shared__ ushort Btr[128][SLDB];
    __shared__ float acs4[4][64];
    __shared__ float dts[4][64];
    __shared__ float decs[4][64];

    {
        const int hh = hgrp * 4 + w;
        float v = adtb[(size_t)(row0 + lane) * NHEADS + hh];
        #pragma unroll
        for (int off = 1; off < 64; off <<= 1) {
            float t = __shfl_up(v, off);
            if (lane >= off) v += t;
        }
        acs4[w][lane] = v;
        float tot = __shfl(v, 63);
        decs[w][lane] = __expf(tot - v);
        acsbuf[(((size_t)b * NCHUNK + c) * NHEADS + hh) * LCHUNK + lane] = v;
        if (lane == 63) chunksum[((size_t)b * NCHUNK + c) * NHEADS + hh] = v;
        dts[w][lane] = dtb[(size_t)(row0 + lane) * NHEADS + hh];
    }
    for (int it = 0; it < 4; ++it) {
        int idx = tid + it * 256;
        int l = idx >> 4, ng = idx & 15;
        const ushort* rp = &xbc[(size_t)(row0 + l) * CONVDIM + DINNER];
        uint4 vb = *(const uint4*)(rp + ng * 8);
        *(uint4*)&U.p1.Bs[l][ng * 8] = vb;
        uint4 vc = *(const uint4*)(rp + DSTATE + ng * 8);
        *(uint4*)&U.p1.Cs[l][ng * 8] = vc;
        const ushort* pv = (const ushort*)&vb;
        #pragma unroll
        for (int j = 0; j < 8; ++j) Btr[ng * 8 + j][l] = pv[j];
    }
    __syncthreads();

    const int wr = w >> 1, wc = w & 1;
    f32x4 accG[2][2];
    #pragma unroll
    for (int i = 0; i < 2; ++i)
        #pragma unroll
        for (int j = 0; j < 2; ++j) accG[i][j] = (f32x4)0.f;
    #pragma unroll
    for (int kt = 0; kt < 4; ++kt) {
        bf16x8 af[2], bfv[2];
        #pragma unroll
        for (int i = 0; i < 2; ++i) af[i]  = *(const bf16x8*)&U.p1.Cs[wr*32 + i*16 + fr][kt*32 + kc*8];
        #pragma unroll
        for (int j = 0; j < 2; ++j) bfv[j] = *(const bf16x8*)&U.p1.Bs[wc*32 + j*16 + fr][kt*32 + kc*8];
        #pragma unroll
        for (int i = 0; i < 2; ++i)
            #pragma unroll
            for (int j = 0; j < 2; ++j)
                accG[i][j] = __builtin_amdgcn_mfma_f32_16x16x32_bf16(af[i], bfv[j], accG[i][j], 0, 0, 0);
    }
    __syncthreads();

    for (int hl = 0; hl < 4; ++hl) {
        const int hh = hgrp * 4 + hl;
        {
            const int p = lane;
            ushort xt[16], xdt[16];
            #pragma unroll
            for (int j = 0; j < 16; ++j) {
                int l = w * 16 + j;
                float xv = bf2f(xbc[(size_t)(row0 + l) * CONVDIM + hh * HEADDIM + p])
                           * dts[hl][l];
                xt[j]  = f2bf(xv);
                xdt[j] = f2bf(xv * decs[hl][l]);
            }
            #pragma unroll
            for (int v = 0; v < 4; ++v) {
                *(ushort4*)&U.p2.Xt [p][w*16 + v*4] = *(ushort4*)&xt[v*4];
                *(ushort4*)&U.p2.Xdt[p][w*16 + v*4] = *(ushort4*)&xdt[v*4];
            }
        }
        #pragma unroll
        for (int i = 0; i < 2; ++i)
            #pragma unroll
            for (int j = 0; j < 2; ++j)
                #pragma unroll
                for (int q = 0; q < 4; ++q) {
                    int l = wr*32 + i*16 + (lane >> 4)*4 + q;
                    int s = wc*32 + j*16 + fr;
                    float v = 0.f;
                    if (s < l)       v = accG[i][j][q] * __expf(acs4[hl][l] - acs4[hl][s]);
                    else if (s == l) v = accG[i][j][q] + Dp[hh] / dts[hl][l];
                    U.p2.Ps[l][s] = f2bf(v);
                }
        __syncthreads();
        {
            f32x4 acc[4];
            #pragma unroll
            for (int j = 0; j < 4; ++j) acc[j] = (f32x4)0.f;
            #pragma unroll
            for (int kt = 0; kt < 2; ++kt) {
                bf16x8 af = *(const bf16x8*)&U.p2.Ps[w*16 + fr][kt*32 + kc*8];
                #pragma unroll
                for (int j = 0; j < 4; ++j) {
                    bf16x8 bfv = *(const bf16x8*)&U.p2.Xt[j*16 + fr][kt*32 + kc*8];
                    acc[j] = __builtin_amdgcn_mfma_f32_16x16x32_bf16(af, bfv, acc[j], 0, 0, 0);
                }
            }
            #pragma unroll
            for (int j = 0; j < 4; ++j)
                #pragma unroll
                for (int q = 0; q < 4; ++q) {
                    int l = w*16 + (lane >> 4)*4 + q;
                    int p = j*16 + fr;
                    ybuf[(size_t)(row0 + l) * DINNER + hh * HEADDIM + p] = f2bf(acc[j][q]);
                }
        }
        {
            f32x4 acc2[4][2];
            #pragma unroll
            for (int mt = 0; mt < 4; ++mt)
                #pragma unroll
                for (int jt = 0; jt < 2; ++jt) acc2[mt][jt] = (f32x4)0.f;
            #pragma unroll
            for (int kt = 0; kt < 2; ++kt) {
                bf16x8 a4[4], b2[2];
                #pragma unroll
                for (int mt = 0; mt < 4; ++mt) a4[mt] = *(const bf16x8*)&U.p2.Xdt[mt*16 + fr][kt*32 + kc*8];
                #pragma unroll
                for (int jt = 0; jt < 2; ++jt) b2[jt] = *(const bf16x8*)&Btr[w*32 + jt*16 + fr][kt*32 + kc*8];
                #pragma unroll
                for (int mt = 0; mt < 4; ++mt)
                    #pragma unroll
                    for (int jt = 0; jt < 2; ++jt)
                        acc2[mt][jt] = __builtin_amdgcn_mfma_f32_16x16x32_bf16(a4[mt], b2[jt], acc2[mt][jt], 0, 0, 0);
            }
            ushort* sb = states + ((((size_t)b * NCHUNK + c) * NHEADS + hh) * HEADDIM) * DSTATE;
            #pragma unroll
            for (int mt = 0; mt < 4; ++mt)
                #pragma unroll
                for (int jt = 0; jt < 2; ++jt)
                    #pragma unroll
                    for (int q = 0; q < 4; ++q) {
                        int p = mt*16 + (lane >> 4)*4 + q;
                        int n = w*32 + jt*16 + fr;
                        sb[(size_t)p * DSTATE + n] = f2bf(acc2[mt][jt][q]);
                    }
        }
        __syncthreads();
    }
}

// ------------------------------------- inter-chunk scan (bf16 states, f32 regs)
__global__ __launch_bounds__(256) void scan_k(ushort* __restrict__ states,
                                              const float* __restrict__ chunksum) {
    const int bid = blockIdx.x;
    const int pq = bid & 3, h = (bid >> 2) & 7, b = bid >> 5;
    const int tid = threadIdx.x;
    float pref[8];
    #pragma unroll
    for (int k = 0; k < 8; ++k) pref[k] = 0.f;
    for (int c = 0; c < NCHUNK; ++c) {
        ushort* base = states + (((size_t)b * NCHUNK + c) * NHEADS + h) * (HEADDIM * DSTATE)
                       + pq * 2048 + tid * 8;
        float dec = __expf(chunksum[((size_t)b * NCHUNK + c) * NHEADS + h]);
        uint4 v = *(const uint4*)base;
        const ushort* pv = (const ushort*)&v;
        ushort outv[8];
        #pragma unroll
        for (int j = 0; j < 8; ++j) {
            float cur = bf2f(pv[j]);
            outv[j] = f2bf(pref[j]);
            pref[j] = dec * pref[j] + cur;
        }
        *(uint4*)base = *(uint4*)outv;
    }
}

// ------------------- Y_off += C @ S^T * ea, then gate+RMSNorm, write bf16 g
#define YLDS 520
__global__ __launch_bounds__(256) void yoff_gate_k(const ushort* __restrict__ xbc,
                                                   const ushort* __restrict__ states,
                                                   const float* __restrict__ acsbuf,
                                                   const ushort* __restrict__ ybuf,
                                                   const ushort* __restrict__ zx,
                                                   const float* __restrict__ nw,
                                                   ushort* __restrict__ gbuf) {
    const int c = blockIdx.x, b = blockIdx.y;
    const int row0 = b * SEQ + c * LCHUNK;
    const int tid = threadIdx.x;
    const int lane = tid & 63, w = tid >> 6;
    const int fr = lane & 15, kc = lane >> 4;
    __shared__ ushort Csh[64][SLDA];
    __shared__ ushort Ssh[64][SLDA];
    __shared__ ushort Ys[64][YLDS];
    __shared__ float eah[64];

    for (int it = 0; it < 4; ++it) {
        int idx = tid + it * 256;
        int l = idx >> 4, ng = idx & 15;
        *(uint4*)&Csh[l][ng * 8] =
            *(const uint4*)&xbc[(size_t)(row0 + l) * CONVDIM + DINNER + DSTATE + ng * 8];
    }
    for (int hl = 0; hl < NHEADS; ++hl) {
        __syncthreads();
        const ushort* sb = states + ((((size_t)b * NCHUNK + c) * NHEADS + hl) * HEADDIM) * DSTATE;
        for (int it = 0; it < 4; ++it) {
            int idx = tid + it * 256;
            int p = idx >> 4, ng = idx & 15;
            *(uint4*)&Ssh[p][ng * 8] = *(const uint4*)&sb[(size_t)p * DSTATE + ng * 8];
        }
        if (tid < 64)
            eah[tid] = __expf(acsbuf[(((size_t)b * NCHUNK + c) * NHEADS + hl) * LCHUNK + tid]);
        __syncthreads();
        f32x4 acc[4];
        #pragma unroll
        for (int j = 0; j < 4; ++j) acc[j] = (f32x4)0.f;
        #pragma unroll
        for (int kt = 0; kt < 4; ++kt) {
            bf16x8 af = *(const bf16x8*)&Csh[w*16 + fr][kt*32 + kc*8];
            #pragma unroll
            for (int j = 0; j < 4; ++j) {
                bf16x8 bfv = *(const bf16x8*)&Ssh[j*16 + fr][kt*32 + kc*8];
                acc[j] = __builtin_amdgcn_mfma_f32_16x16x32_bf16(af, bfv, acc[j], 0, 0, 0);
            }
        }
        #pragma unroll
        for (int j = 0; j < 4; ++j)
            #pragma unroll
            for (int q = 0; q < 4; ++q) {
                int l = w*16 + (lane >> 4)*4 + q;
                int p = j*16 + fr;
                float val = bf2f(ybuf[(size_t)(row0 + l) * DINNER + hl * HEADDIM + p])
                            + acc[j][q] * eah[l];
                Ys[l][hl * HEADDIM + p] = f2bf(val);
            }
    }
    __syncthreads();
    float nwv[8];
    #pragma unroll
    for (int j = 0; j < 8; ++j) nwv[j] = nw[lane * 8 + j];
    for (int i = 0; i < 16; ++i) {
        int l = w * 16 + i;
        int row = row0 + l;
        uint4 zv = *(const uint4*)&zx[(size_t)row * ZXLD + lane * 8];
        const ushort* pz = (const ushort*)&zv;
        float g[8], ss = 0.f;
        #pragma unroll
        for (int j = 0; j < 8; ++j) {
            float y = bf2f(Ys[l][lane * 8 + j]);
            float z = bf2f(pz[j]);
            float sz = z / (1.f + __expf(-z));
            g[j] = y * sz;
            ss += g[j] * g[j];
        }
        #pragma unroll
        for (int off = 32; off; off >>= 1) ss += __shfl_xor(ss, off);
        float r = rsqrtf(ss / (float)DINNER + EPSV);
        ushort res[8];
        #pragma unroll
        for (int j = 0; j < 8; ++j) res[j] = f2bf(g[j] * r * nwv[j]);
        *(uint4*)&gbuf[(size_t)row * DINNER + lane * 8] = *(uint4*)res;
    }
}

// ---------------------------------------------------------------- launch
extern "C" void kernel_launch(void* const* d_in, const int* in_sizes, int n_in,
                              void* d_out, int out_size, void* d_ws, size_t ws_size,
                              hipStream_t stream) {
    const float* u       = (const float*)d_in[0];
    const float* W_in    = (const float*)d_in[1];
    const float* conv_w  = (const float*)d_in[2];
    const float* conv_b  = (const float*)d_in[3];
    const float* dt_bias = (const float*)d_in[4];
    const float* A_log   = (const float*)d_in[5];
    const float* Dp      = (const float*)d_in[6];
    const float* norm_w  = (const float*)d_in[7];
    const float* W_out   = (const float*)d_in[8];
    float* out = (float*)d_out;

    char* p = (char*)d_ws;
    ushort* zx       = (ushort*)p; p += (size_t)ROWS * ZXLD * sizeof(ushort);
    ushort* ybuf     = (ushort*)p; p += (size_t)ROWS * DINNER * sizeof(ushort);
    ushort* gbuf     = (ushort*)p; p += (size_t)ROWS * DINNER * sizeof(ushort);
    ushort* states   = (ushort*)p; p += (size_t)BATCHN * NCHUNK * NHEADS * HEADDIM * DSTATE * sizeof(ushort);
    ushort* xbc      = (ushort*)p; p += (size_t)ROWS * CONVDIM * sizeof(ushort);
    ushort* ubf      = (ushort*)p; p += (size_t)ROWS * DMODEL * sizeof(ushort);
    float*  dtb      = (float*)p;  p += (size_t)ROWS * NHEADS  * sizeof(float);
    float*  adtb     = (float*)p;  p += (size_t)ROWS * NHEADS  * sizeof(float);
    float*  chunksum = (float*)p;  p += (size_t)BATCHN * NCHUNK * NHEADS * sizeof(float);
    float*  acsbuf   = (float*)p;  p += (size_t)BATCHN * NCHUNK * NHEADS * LCHUNK * sizeof(float);
    ushort* WtA      = (ushort*)p; p += (size_t)ZXLD * DMODEL * sizeof(ushort);
    ushort* WtB      = (ushort*)p; p += (size_t)DMODEL * DINNER * sizeof(ushort);

    // 1. dt GEMV (exact f32) + u->bf16 cast
    dt_cast_k<<<ROWS/32, 256, 0, stream>>>(u, W_in, dt_bias, A_log, ubf, dtb, adtb);
    // 2. weight transposes
    transpose_cast2_k<<<448, 256, 0, stream>>>(W_in, W_out, WtA, WtB);
    // 3. in-proj -> bf16 zx, with fused depthwise conv+SiLU (rows 3..127/tile)
    gemm_bf16<ushort, true><<<(ZXLD/128)*(ROWS/128), 256, 0, stream>>>(
        ubf, WtA, zx, ROWS, ZXLD, DMODEL, ZXLD/128, conv_w, conv_b, xbc);
    // 4. conv boundary rows (0..2 of each 128-row tile)
    conv_fix_k<<<ROWS/128, 256, 0, stream>>>(zx, conv_w, conv_b, xbc);
    // 5. SSD chunk kernel (hgrp fastest for B/C L2 sharing)
    ssd_mfma_k<<<dim3(2, NCHUNK, BATCHN), 256, 0, stream>>>(
        xbc, dtb, adtb, Dp, ybuf, states, acsbuf, chunksum);
    // 6. inter-chunk scan
    scan_k<<<BATCHN*NHEADS*4, 256, 0, stream>>>(states, chunksum);
    // 7. Y_off + gate + RMSNorm
    yoff_gate_k<<<dim3(NCHUNK, BATCHN), 256, 0, stream>>>(
        xbc, states, acsbuf, ybuf, zx, norm_w, gbuf);
    // 8. out-proj
    gemm_bf16<float, false><<<(DMODEL/128)*(ROWS/128), 256, 0, stream>>>(
        gbuf, WtB, out, ROWS, DMODEL, DINNER, DMODEL/128, nullptr, nullptr, nullptr);
}

// Round 11
// 130.159 us; speedup vs baseline: 1.1463x; 1.0908x over previous
//
#include <hip/hip_runtime.h>
#include <hip/hip_bf16.h>
#include <math.h>

#define BATCHN  16
#define SEQ     1024
#define DMODEL  256
#define DSTATE  128
#define HEADDIM 64
#define DINNER  512
#define NHEADS  8
#define CONVDIM 768
#define DINPROJ 1288
#define ZXLD    1280
#define KCONV   4
#define NCHUNK  16
#define LCHUNK  64
#define EPSV    1e-5f
#define ROWS    (BATCHN*SEQ)

typedef __attribute__((ext_vector_type(8))) __bf16 bf16x8;
typedef __attribute__((ext_vector_type(4))) float  f32x4;

__device__ inline ushort f2bf(float f) {
    union { float f; uint32_t u; } v; v.f = f;
    uint32_t r = v.u + 0x7fff + ((v.u >> 16) & 1);
    return (ushort)(r >> 16);
}
__device__ inline float bf2f(ushort u) {
    union { uint32_t u; float f; } v; v.u = ((uint32_t)u) << 16;
    return v.f;
}

// ---------- prep: dt GEMV + u->bf16 cast (blocks 0..511) | W transposes (512..959)
__global__ __launch_bounds__(256) void prep_k(const float* __restrict__ u,
                                              const float* __restrict__ W_in,
                                              const float* __restrict__ W_out,
                                              const float* __restrict__ dt_bias,
                                              const float* __restrict__ A_log,
                                              ushort* __restrict__ ubf,
                                              float* __restrict__ dtb,
                                              float* __restrict__ adtb,
                                              ushort* __restrict__ WtA,
                                              ushort* __restrict__ WtB) {
    __shared__ union {
        struct { float Uld[32][264]; float Ws[DMODEL][NHEADS]; } d;
        float Ts[32][33];
    } S;
    const int tid = threadIdx.x;
    if (blockIdx.x < 512) {
        // ---- dt GEMV (exact f32) + cast
        #pragma unroll
        for (int j = 0; j < 8; ++j) {
            int idx = tid + j * 256;
            S.d.Ws[idx >> 3][idx & 7] = W_in[(size_t)(idx >> 3) * DINPROJ + 1280 + (idx & 7)];
        }
        const int row0 = blockIdx.x * 32;
        #pragma unroll
        for (int v = 0; v < 8; ++v) {
            int e = v * 1024 + tid * 4;
            int r = e >> 8, cc = e & 255;
            float4 x = *(const float4*)&u[(size_t)(row0 + r) * DMODEL + cc];
            *(float4*)&S.d.Uld[r][cc] = x;
            ushort t4[4];
            t4[0]=f2bf(x.x); t4[1]=f2bf(x.y); t4[2]=f2bf(x.z); t4[3]=f2bf(x.w);
            *(ushort4*)&ubf[(size_t)(row0 + r) * DMODEL + cc] = *(ushort4*)t4;
        }
        __syncthreads();
        const int row = tid >> 3, h = tid & 7;
        float acc = 0.f;
        #pragma unroll 8
        for (int k = 0; k < DMODEL; k += 4) {
            float4 uv = *(const float4*)&S.d.Uld[row][k];
            acc += uv.x * S.d.Ws[k][h] + uv.y * S.d.Ws[k+1][h]
                 + uv.z * S.d.Ws[k+2][h] + uv.w * S.d.Ws[k+3][h];
        }
        float v = acc + dt_bias[h];
        float dt = (v > 20.f) ? v : log1pf(__expf(v));
        dtb [(size_t)(row0 + row) * NHEADS + h] = dt;
        adtb[(size_t)(row0 + row) * NHEADS + h] = dt * (-__expf(A_log[h]));
    } else {
        // ---- weight transpose+cast
        int bid = blockIdx.x - 512;
        const float* src; ushort* dst; int K, ldsrc, nx;
        if (bid < 320) { src = W_in;  dst = WtA; K = DMODEL; ldsrc = DINPROJ; nx = 40; }
        else { bid -= 320; src = W_out; dst = WtB; K = DINNER; ldsrc = DMODEL; nx = 8; }
        const int n0 = (bid % nx) * 32, k0 = (bid / nx) * 32;
        const int tx = tid & 31, ty = tid >> 5;
        #pragma unroll
        for (int j = 0; j < 4; ++j) {
            int kl = ty * 4 + j;
            S.Ts[kl][tx] = src[(size_t)(k0 + kl) * ldsrc + n0 + tx];
        }
        __syncthreads();
        #pragma unroll
        for (int j = 0; j < 4; ++j) {
            int nl = ty * 4 + j;
            dst[(size_t)(n0 + nl) * K + k0 + tx] = f2bf(S.Ts[tx][nl]);
        }
    }
}

// ------------------------------------------------------- bf16 MFMA GEMM
#define LDSW 72
template<typename CT>
__global__ __launch_bounds__(256) void gemm_bf16(const ushort* __restrict__ A,
                                                 const ushort* __restrict__ Bt,
                                                 CT* __restrict__ C,
                                                 int M, int N, int K, int nx) {
    __shared__ ushort As[128 * LDSW];
    __shared__ ushort Bs[128 * LDSW];
    const int tid  = threadIdx.x;
    const int nwg  = gridDim.x;
    const int work = (blockIdx.x & 7) * (nwg >> 3) + (blockIdx.x >> 3);
    const int m0 = (work / nx) * 128, n0 = (work % nx) * 128;
    const int wid = tid >> 6, lane = tid & 63;
    const int wr = wid >> 1, wc = wid & 1;
    const int r = tid >> 1, kq = tid & 1;
    const int fr = lane & 15, kc = lane >> 4;

    f32x4 acc[4][4];
    #pragma unroll
    for (int i = 0; i < 4; ++i)
        #pragma unroll
        for (int j = 0; j < 4; ++j) acc[i][j] = (f32x4)0.f;

    for (int kt = 0; kt < K; kt += 64) {
        const ushort* ap = &A [(size_t)(m0 + r) * K + kt + kq * 32];
        const ushort* bp = &Bt[(size_t)(n0 + r) * K + kt + kq * 32];
        #pragma unroll
        for (int v = 0; v < 4; ++v) {
            *(uint4*)&As[r * LDSW + kq * 32 + v * 8] = *(const uint4*)(ap + v * 8);
            *(uint4*)&Bs[r * LDSW + kq * 32 + v * 8] = *(const uint4*)(bp + v * 8);
        }
        __syncthreads();
        #pragma unroll
        for (int kk = 0; kk < 2; ++kk) {
            bf16x8 af[4], bfv[4];
            #pragma unroll
            for (int i = 0; i < 4; ++i) {
                af[i]  = *(const bf16x8*)&As[(wr * 64 + i * 16 + fr) * LDSW + kk * 32 + kc * 8];
                bfv[i] = *(const bf16x8*)&Bs[(wc * 64 + i * 16 + fr) * LDSW + kk * 32 + kc * 8];
            }
            #pragma unroll
            for (int i = 0; i < 4; ++i)
                #pragma unroll
                for (int j = 0; j < 4; ++j)
                    acc[i][j] = __builtin_amdgcn_mfma_f32_16x16x32_bf16(af[i], bfv[j], acc[i][j], 0, 0, 0);
        }
        __syncthreads();
    }
    #pragma unroll
    for (int i = 0; i < 4; ++i)
        #pragma unroll
        for (int j = 0; j < 4; ++j)
            #pragma unroll
            for (int q = 0; q < 4; ++q) {
                int rr = m0 + wr * 64 + i * 16 + (lane >> 4) * 4 + q;
                int cc = n0 + wc * 64 + j * 16 + (lane & 15);
                if constexpr (sizeof(CT) == 4) C[(size_t)rr * N + cc] = acc[i][j][q];
                else                           C[(size_t)rr * N + cc] = f2bf(acc[i][j][q]);
            }
}

// ------------------- depthwise conv + SiLU: LDS weights, 4 t-steps/thread
__global__ __launch_bounds__(256) void conv_silu_k(const ushort* __restrict__ zx,
                                                   const float* __restrict__ cw,
                                                   const float* __restrict__ cb,
                                                   ushort* __restrict__ out) {
    __shared__ float cws[KCONV][CONVDIM];
    __shared__ float cbs[CONVDIM];
    const int tid = threadIdx.x;
    #pragma unroll
    for (int it = 0; it < 3; ++it) {
        int i = tid + it * 256;
        cbs[i] = cb[i];
        #pragma unroll
        for (int k = 0; k < KCONV; ++k) cws[k][i] = cw[i * KCONV + k];
    }
    __syncthreads();

    const int idx = blockIdx.x * 256 + tid;
    const int cg = idx % 96, btq = idx / 96;
    const int c0 = cg * 8;
    const int bt0 = btq * 4;
    const int t0 = bt0 & (SEQ - 1);

    float wv[KCONV][8], bias[8];
    #pragma unroll
    for (int j = 0; j < 8; ++j) bias[j] = cbs[c0 + j];
    #pragma unroll
    for (int k = 0; k < KCONV; ++k) {
        float4 a = *(const float4*)&cws[k][c0];
        float4 b = *(const float4*)&cws[k][c0 + 4];
        wv[k][0] = a.x; wv[k][1] = a.y; wv[k][2] = a.z; wv[k][3] = a.w;
        wv[k][4] = b.x; wv[k][5] = b.y; wv[k][6] = b.z; wv[k][7] = b.w;
    }
    float xr[7][8];
    #pragma unroll
    for (int r = 0; r < 7; ++r) {
        int tt = t0 - 3 + r;
        if (tt >= 0) {
            uint4 v = *(const uint4*)&zx[(size_t)(bt0 - 3 + r) * ZXLD + DINNER + c0];
            const ushort* pv = (const ushort*)&v;
            #pragma unroll
            for (int j = 0; j < 8; ++j) xr[r][j] = bf2f(pv[j]);
        } else {
            #pragma unroll
            for (int j = 0; j < 8; ++j) xr[r][j] = 0.f;
        }
    }
    #pragma unroll
    for (int dt = 0; dt < 4; ++dt) {
        float acc[8];
        #pragma unroll
        for (int j = 0; j < 8; ++j) acc[j] = bias[j];
        #pragma unroll
        for (int k = 0; k < KCONV; ++k)
            #pragma unroll
            for (int j = 0; j < 8; ++j) acc[j] += xr[dt + k][j] * wv[k][j];
        ushort res[8];
        #pragma unroll
        for (int j = 0; j < 8; ++j)
            res[j] = f2bf(acc[j] / (1.f + __expf(-acc[j])));
        *(uint4*)&out[(size_t)(bt0 + dt) * CONVDIM + c0] = *(uint4*)res;
    }
}

// -------------------------------------------------- SSD MFMA kernel (XCD-swizzled)
#define SLDA 136
#define SLDB 72
__global__ __launch_bounds__(256) void ssd_mfma_k(const ushort* __restrict__ xbc,
                                                  const float* __restrict__ dtb,
                                                  const float* __restrict__ adtb,
                                                  const float* __restrict__ Dp,
                                                  ushort* __restrict__ ybuf,
                                                  ushort* __restrict__ states,
                                                  float* __restrict__ acsbuf,
                                                  float* __restrict__ chunksum) {
    // 512 blocks; XCD-chunked so hgrp pairs (same b,c) share an XCD L2
    const int wk = (blockIdx.x & 7) * 64 + (blockIdx.x >> 3);
    const int hgrp = wk & 1, c = (wk >> 1) & 15, b = wk >> 5;
    const int row0 = b * SEQ + c * LCHUNK;
    const int tid = threadIdx.x;
    const int lane = tid & 63, w = tid >> 6;
    const int fr = lane & 15, kc = lane >> 4;

    __shared__ union {
        struct { ushort Bs[64][SLDA]; ushort Cs[64][SLDA]; } p1;
        struct { ushort Ps[64][SLDB]; ushort Xt[64][SLDB]; ushort Xdt[64][SLDB]; } p2;
    } U;
    __shared__ ushort Btr[128][SLDB];
    __shared__ float acs4[4][64];
    __shared__ float dts[4][64];
    __shared__ float decs[4][64];

    {
        const int hh = hgrp * 4 + w;
        float v = adtb[(size_t)(row0 + lane) * NHEADS + hh];
        #pragma unroll
        for (int off = 1; off < 64; off <<= 1) {
            float t = __shfl_up(v, off);
            if (lane >= off) v += t;
        }
        acs4[w][lane] = v;
        float tot = __shfl(v, 63);
        decs[w][lane] = __expf(tot - v);
        acsbuf[(((size_t)b * NCHUNK + c) * NHEADS + hh) * LCHUNK + lane] = v;
        if (lane == 63) chunksum[((size_t)b * NCHUNK + c) * NHEADS + hh] = v;
        dts[w][lane] = dtb[(size_t)(row0 + lane) * NHEADS + hh];
    }
    for (int it = 0; it < 4; ++it) {
        int idx = tid + it * 256;
        int l = idx >> 4, ng = idx & 15;
        const ushort* rp = &xbc[(size_t)(row0 + l) * CONVDIM + DINNER];
        uint4 vb = *(const uint4*)(rp + ng * 8);
        *(uint4*)&U.p1.Bs[l][ng * 8] = vb;
        uint4 vc = *(const uint4*)(rp + DSTATE + ng * 8);
        *(uint4*)&U.p1.Cs[l][ng * 8] = vc;
        const ushort* pv = (const ushort*)&vb;
        #pragma unroll
        for (int j = 0; j < 8; ++j) Btr[ng * 8 + j][l] = pv[j];
    }
    __syncthreads();

    const int wr = w >> 1, wc = w & 1;
    f32x4 accG[2][2];
    #pragma unroll
    for (int i = 0; i < 2; ++i)
        #pragma unroll
        for (int j = 0; j < 2; ++j) accG[i][j] = (f32x4)0.f;
    #pragma unroll
    for (int kt = 0; kt < 4; ++kt) {
        bf16x8 af[2], bfv[2];
        #pragma unroll
        for (int i = 0; i < 2; ++i) af[i]  = *(const bf16x8*)&U.p1.Cs[wr*32 + i*16 + fr][kt*32 + kc*8];
        #pragma unroll
        for (int j = 0; j < 2; ++j) bfv[j] = *(const bf16x8*)&U.p1.Bs[wc*32 + j*16 + fr][kt*32 + kc*8];
        #pragma unroll
        for (int i = 0; i < 2; ++i)
            #pragma unroll
            for (int j = 0; j < 2; ++j)
                accG[i][j] = __builtin_amdgcn_mfma_f32_16x16x32_bf16(af[i], bfv[j], accG[i][j], 0, 0, 0);
    }
    __syncthreads();

    for (int hl = 0; hl < 4; ++hl) {
        const int hh = hgrp * 4 + hl;
        {
            const int p = lane;
            ushort xt[16], xdt[16];
            #pragma unroll
            for (int j = 0; j < 16; ++j) {
                int l = w * 16 + j;
                float xv = bf2f(xbc[(size_t)(row0 + l) * CONVDIM + hh * HEADDIM + p])
                           * dts[hl][l];
                xt[j]  = f2bf(xv);
                xdt[j] = f2bf(xv * decs[hl][l]);
            }
            #pragma unroll
            for (int v = 0; v < 4; ++v) {
                *(ushort4*)&U.p2.Xt [p][w*16 + v*4] = *(ushort4*)&xt[v*4];
                *(ushort4*)&U.p2.Xdt[p][w*16 + v*4] = *(ushort4*)&xdt[v*4];
            }
        }
        #pragma unroll
        for (int i = 0; i < 2; ++i)
            #pragma unroll
            for (int j = 0; j < 2; ++j)
                #pragma unroll
                for (int q = 0; q < 4; ++q) {
                    int l = wr*32 + i*16 + (lane >> 4)*4 + q;
                    int s = wc*32 + j*16 + fr;
                    float v = 0.f;
                    if (s < l)       v = accG[i][j][q] * __expf(acs4[hl][l] - acs4[hl][s]);
                    else if (s == l) v = accG[i][j][q] + Dp[hh] / dts[hl][l];
                    U.p2.Ps[l][s] = f2bf(v);
                }
        __syncthreads();
        {
            f32x4 acc[4];
            #pragma unroll
            for (int j = 0; j < 4; ++j) acc[j] = (f32x4)0.f;
            #pragma unroll
            for (int kt = 0; kt < 2; ++kt) {
                bf16x8 af = *(const bf16x8*)&U.p2.Ps[w*16 + fr][kt*32 + kc*8];
                #pragma unroll
                for (int j = 0; j < 4; ++j) {
                    bf16x8 bfv = *(const bf16x8*)&U.p2.Xt[j*16 + fr][kt*32 + kc*8];
                    acc[j] = __builtin_amdgcn_mfma_f32_16x16x32_bf16(af, bfv, acc[j], 0, 0, 0);
                }
            }
            #pragma unroll
            for (int j = 0; j < 4; ++j)
                #pragma unroll
                for (int q = 0; q < 4; ++q) {
                    int l = w*16 + (lane >> 4)*4 + q;
                    int p = j*16 + fr;
                    ybuf[(size_t)(row0 + l) * DINNER + hh * HEADDIM + p] = f2bf(acc[j][q]);
                }
        }
        {
            f32x4 acc2[4][2];
            #pragma unroll
            for (int mt = 0; mt < 4; ++mt)
                #pragma unroll
                for (int jt = 0; jt < 2; ++jt) acc2[mt][jt] = (f32x4)0.f;
            #pragma unroll
            for (int kt = 0; kt < 2; ++kt) {
                bf16x8 a4[4], b2[2];
                #pragma unroll
                for (int mt = 0; mt < 4; ++mt) a4[mt] = *(const bf16x8*)&U.p2.Xdt[mt*16 + fr][kt*32 + kc*8];
                #pragma unroll
                for (int jt = 0; jt < 2; ++jt) b2[jt] = *(const bf16x8*)&Btr[w*32 + jt*16 + fr][kt*32 + kc*8];
                #pragma unroll
                for (int mt = 0; mt < 4; ++mt)
                    #pragma unroll
                    for (int jt = 0; jt < 2; ++jt)
                        acc2[mt][jt] = __builtin_amdgcn_mfma_f32_16x16x32_bf16(a4[mt], b2[jt], acc2[mt][jt], 0, 0, 0);
            }
            ushort* sb = states + ((((size_t)b * NCHUNK + c) * NHEADS + hh) * HEADDIM) * DSTATE;
            #pragma unroll
            for (int mt = 0; mt < 4; ++mt)
                #pragma unroll
                for (int jt = 0; jt < 2; ++jt)
                    #pragma unroll
                    for (int q = 0; q < 4; ++q) {
                        int p = mt*16 + (lane >> 4)*4 + q;
                        int n = w*32 + jt*16 + fr;
                        sb[(size_t)p * DSTATE + n] = f2bf(acc2[mt][jt][q]);
                    }
        }
        __syncthreads();
    }
}

// ------------------------------------- inter-chunk scan (bf16 states, f32 regs)
__global__ __launch_bounds__(256) void scan_k(ushort* __restrict__ states,
                                              const float* __restrict__ chunksum) {
    const int bid = blockIdx.x;
    const int pq = bid & 3, h = (bid >> 2) & 7, b = bid >> 5;
    const int tid = threadIdx.x;
    float pref[8];
    #pragma unroll
    for (int k = 0; k < 8; ++k) pref[k] = 0.f;
    for (int c = 0; c < NCHUNK; ++c) {
        ushort* base = states + (((size_t)b * NCHUNK + c) * NHEADS + h) * (HEADDIM * DSTATE)
                       + pq * 2048 + tid * 8;
        float dec = __expf(chunksum[((size_t)b * NCHUNK + c) * NHEADS + h]);
        uint4 v = *(const uint4*)base;
        const ushort* pv = (const ushort*)&v;
        ushort outv[8];
        #pragma unroll
        for (int j = 0; j < 8; ++j) {
            float cur = bf2f(pv[j]);
            outv[j] = f2bf(pref[j]);
            pref[j] = dec * pref[j] + cur;
        }
        *(uint4*)base = *(uint4*)outv;
    }
}

// ------------------- Y_off += C @ S^T * ea, then gate+RMSNorm, write bf16 g
#define YLDS 520
__global__ __launch_bounds__(256) void yoff_gate_k(const ushort* __restrict__ xbc,
                                                   const ushort* __restrict__ states,
                                                   const float* __restrict__ acsbuf,
                                                   const ushort* __restrict__ ybuf,
                                                   const ushort* __restrict__ zx,
                                                   const float* __restrict__ nw,
                                                   ushort* __restrict__ gbuf) {
    const int c = blockIdx.x, b = blockIdx.y;
    const int row0 = b * SEQ + c * LCHUNK;
    const int tid = threadIdx.x;
    const int lane = tid & 63, w = tid >> 6;
    const int fr = lane & 15, kc = lane >> 4;
    __shared__ ushort Csh[64][SLDA];
    __shared__ ushort Ssh[64][SLDA];
    __shared__ ushort Ys[64][YLDS];
    __shared__ float eah[64];

    for (int it = 0; it < 4; ++it) {
        int idx = tid + it * 256;
        int l = idx >> 4, ng = idx & 15;
        *(uint4*)&Csh[l][ng * 8] =
            *(const uint4*)&xbc[(size_t)(row0 + l) * CONVDIM + DINNER + DSTATE + ng * 8];
    }
    for (int hl = 0; hl < NHEADS; ++hl) {
        __syncthreads();
        const ushort* sb = states + ((((size_t)b * NCHUNK + c) * NHEADS + hl) * HEADDIM) * DSTATE;
        for (int it = 0; it < 4; ++it) {
            int idx = tid + it * 256;
            int p = idx >> 4, ng = idx & 15;
            *(uint4*)&Ssh[p][ng * 8] = *(const uint4*)&sb[(size_t)p * DSTATE + ng * 8];
        }
        if (tid < 64)
            eah[tid] = __expf(acsbuf[(((size_t)b * NCHUNK + c) * NHEADS + hl) * LCHUNK + tid]);
        __syncthreads();
        f32x4 acc[4];
        #pragma unroll
        for (int j = 0; j < 4; ++j) acc[j] = (f32x4)0.f;
        #pragma unroll
        for (int kt = 0; kt < 4; ++kt) {
            bf16x8 af = *(const bf16x8*)&Csh[w*16 + fr][kt*32 + kc*8];
            #pragma unroll
            for (int j = 0; j < 4; ++j) {
                bf16x8 bfv = *(const bf16x8*)&Ssh[j*16 + fr][kt*32 + kc*8];
                acc[j] = __builtin_amdgcn_mfma_f32_16x16x32_bf16(af, bfv, acc[j], 0, 0, 0);
            }
        }
        #pragma unroll
        for (int j = 0; j < 4; ++j)
            #pragma unroll
            for (int q = 0; q < 4; ++q) {
                int l = w*16 + (lane >> 4)*4 + q;
                int p = j*16 + fr;
                float val = bf2f(ybuf[(size_t)(row0 + l) * DINNER + hl * HEADDIM + p])
                            + acc[j][q] * eah[l];
                Ys[l][hl * HEADDIM + p] = f2bf(val);
            }
    }
    __syncthreads();
    float nwv[8];
    #pragma unroll
    for (int j = 0; j < 8; ++j) nwv[j] = nw[lane * 8 + j];
    for (int i = 0; i < 16; ++i) {
        int l = w * 16 + i;
        int row = row0 + l;
        uint4 zv = *(const uint4*)&zx[(size_t)row * ZXLD + lane * 8];
        const ushort* pz = (const ushort*)&zv;
        float g[8], ss = 0.f;
        #pragma unroll
        for (int j = 0; j < 8; ++j) {
            float y = bf2f(Ys[l][lane * 8 + j]);
            float z = bf2f(pz[j]);
            float sz = z / (1.f + __expf(-z));
            g[j] = y * sz;
            ss += g[j] * g[j];
        }
        #pragma unroll
        for (int off = 32; off; off >>= 1) ss += __shfl_xor(ss, off);
        float r = rsqrtf(ss / (float)DINNER + EPSV);
        ushort res[8];
        #pragma unroll
        for (int j = 0; j < 8; ++j) res[j] = f2bf(g[j] * r * nwv[j]);
        *(uint4*)&gbuf[(size_t)row * DINNER + lane * 8] = *(uint4*)res;
    }
}

// ---------------------------------------------------------------- launch
extern "C" void kernel_launch(void* const* d_in, const int* in_sizes, int n_in,
                              void* d_out, int out_size, void* d_ws, size_t ws_size,
                              hipStream_t stream) {
    const float* u       = (const float*)d_in[0];
    const float* W_in    = (const float*)d_in[1];
    const float* conv_w  = (const float*)d_in[2];
    const float* conv_b  = (const float*)d_in[3];
    const float* dt_bias = (const float*)d_in[4];
    const float* A_log   = (const float*)d_in[5];
    const float* Dp      = (const float*)d_in[6];
    const float* norm_w  = (const float*)d_in[7];
    const float* W_out   = (const float*)d_in[8];
    float* out = (float*)d_out;

    char* p = (char*)d_ws;
    ushort* zx       = (ushort*)p; p += (size_t)ROWS * ZXLD * sizeof(ushort);
    ushort* ybuf     = (ushort*)p; p += (size_t)ROWS * DINNER * sizeof(ushort);
    ushort* gbuf     = (ushort*)p; p += (size_t)ROWS * DINNER * sizeof(ushort);
    ushort* states   = (ushort*)p; p += (size_t)BATCHN * NCHUNK * NHEADS * HEADDIM * DSTATE * sizeof(ushort);
    ushort* xbc      = (ushort*)p; p += (size_t)ROWS * CONVDIM * sizeof(ushort);
    ushort* ubf      = (ushort*)p; p += (size_t)ROWS * DMODEL * sizeof(ushort);
    float*  dtb      = (float*)p;  p += (size_t)ROWS * NHEADS  * sizeof(float);
    float*  adtb     = (float*)p;  p += (size_t)ROWS * NHEADS  * sizeof(float);
    float*  chunksum = (float*)p;  p += (size_t)BATCHN * NCHUNK * NHEADS * sizeof(float);
    float*  acsbuf   = (float*)p;  p += (size_t)BATCHN * NCHUNK * NHEADS * LCHUNK * sizeof(float);
    ushort* WtA      = (ushort*)p; p += (size_t)ZXLD * DMODEL * sizeof(ushort);
    ushort* WtB      = (ushort*)p; p += (size_t)DMODEL * DINNER * sizeof(ushort);

    // 1. dt GEMV + u cast + weight transposes (one dispatch)
    prep_k<<<960, 256, 0, stream>>>(u, W_in, W_out, dt_bias, A_log,
                                    ubf, dtb, adtb, WtA, WtB);
    // 2. in-proj -> bf16 zx
    gemm_bf16<ushort><<<(ZXLD/128)*(ROWS/128), 256, 0, stream>>>(
        ubf, WtA, zx, ROWS, ZXLD, DMODEL, ZXLD/128);
    // 3. depthwise conv + silu
    conv_silu_k<<<(ROWS/4)*96/256, 256, 0, stream>>>(zx, conv_w, conv_b, xbc);
    // 4. SSD chunk kernel (XCD-chunked 1-D grid)
    ssd_mfma_k<<<512, 256, 0, stream>>>(
        xbc, dtb, adtb, Dp, ybuf, states, acsbuf, chunksum);
    // 5. inter-chunk scan
    scan_k<<<BATCHN*NHEADS*4, 256, 0, stream>>>(states, chunksum);
    // 6. Y_off + gate + RMSNorm
    yoff_gate_k<<<dim3(NCHUNK, BATCHN), 256, 0, stream>>>(
        xbc, states, acsbuf, ybuf, zx, norm_w, gbuf);
    // 7. out-proj
    gemm_bf16<float><<<(DMODEL/128)*(ROWS/128), 256, 0, stream>>>(
        gbuf, WtB, out, ROWS, DMODEL, DINNER, DMODEL/128);
}

// Round 12
// 125.411 us; speedup vs baseline: 1.1897x; 1.0379x over previous
//
#include <hip/hip_runtime.h>
#include <hip/hip_bf16.h>
#include <math.h>

#define BATCHN  16
#define SEQ     1024
#define DMODEL  256
#define DSTATE  128
#define HEADDIM 64
#define DINNER  512
#define NHEADS  8
#define CONVDIM 768
#define DINPROJ 1288
#define ZXLD    1280
#define KCONV   4
#define NCHUNK  16
#define LCHUNK  64
#define EPSV    1e-5f
#define ROWS    (BATCHN*SEQ)

typedef __attribute__((ext_vector_type(8))) __bf16 bf16x8;
typedef __attribute__((ext_vector_type(4))) float  f32x4;

__device__ inline ushort f2bf(float f) {
    union { float f; uint32_t u; } v; v.f = f;
    uint32_t r = v.u + 0x7fff + ((v.u >> 16) & 1);
    return (ushort)(r >> 16);
}
__device__ inline float bf2f(ushort u) {
    union { uint32_t u; float f; } v; v.u = ((uint32_t)u) << 16;
    return v.f;
}

// ---------- prep: dt GEMV + u->bf16 cast (blocks 0..511) | W transposes (512..959)
__global__ __launch_bounds__(256) void prep_k(const float* __restrict__ u,
                                              const float* __restrict__ W_in,
                                              const float* __restrict__ W_out,
                                              const float* __restrict__ dt_bias,
                                              const float* __restrict__ A_log,
                                              ushort* __restrict__ ubf,
                                              float* __restrict__ dtb,
                                              float* __restrict__ adtb,
                                              ushort* __restrict__ WtA,
                                              ushort* __restrict__ WtB) {
    __shared__ union {
        struct { float Uld[32][264]; float Ws[DMODEL][NHEADS]; } d;
        float Ts[32][33];
    } S;
    const int tid = threadIdx.x;
    if (blockIdx.x < 512) {
        #pragma unroll
        for (int j = 0; j < 8; ++j) {
            int idx = tid + j * 256;
            S.d.Ws[idx >> 3][idx & 7] = W_in[(size_t)(idx >> 3) * DINPROJ + 1280 + (idx & 7)];
        }
        const int row0 = blockIdx.x * 32;
        #pragma unroll
        for (int v = 0; v < 8; ++v) {
            int e = v * 1024 + tid * 4;
            int r = e >> 8, cc = e & 255;
            float4 x = *(const float4*)&u[(size_t)(row0 + r) * DMODEL + cc];
            *(float4*)&S.d.Uld[r][cc] = x;
            ushort t4[4];
            t4[0]=f2bf(x.x); t4[1]=f2bf(x.y); t4[2]=f2bf(x.z); t4[3]=f2bf(x.w);
            *(ushort4*)&ubf[(size_t)(row0 + r) * DMODEL + cc] = *(ushort4*)t4;
        }
        __syncthreads();
        const int row = tid >> 3, h = tid & 7;
        float acc = 0.f;
        #pragma unroll 8
        for (int k = 0; k < DMODEL; k += 4) {
            float4 uv = *(const float4*)&S.d.Uld[row][k];
            acc += uv.x * S.d.Ws[k][h] + uv.y * S.d.Ws[k+1][h]
                 + uv.z * S.d.Ws[k+2][h] + uv.w * S.d.Ws[k+3][h];
        }
        float v = acc + dt_bias[h];
        float dt = (v > 20.f) ? v : log1pf(__expf(v));
        dtb [(size_t)(row0 + row) * NHEADS + h] = dt;
        adtb[(size_t)(row0 + row) * NHEADS + h] = dt * (-__expf(A_log[h]));
    } else {
        int bid = blockIdx.x - 512;
        const float* src; ushort* dst; int K, ldsrc, nx;
        if (bid < 320) { src = W_in;  dst = WtA; K = DMODEL; ldsrc = DINPROJ; nx = 40; }
        else { bid -= 320; src = W_out; dst = WtB; K = DINNER; ldsrc = DMODEL; nx = 8; }
        const int n0 = (bid % nx) * 32, k0 = (bid / nx) * 32;
        const int tx = tid & 31, ty = tid >> 5;
        #pragma unroll
        for (int j = 0; j < 4; ++j) {
            int kl = ty * 4 + j;
            S.Ts[kl][tx] = src[(size_t)(k0 + kl) * ldsrc + n0 + tx];
        }
        __syncthreads();
        #pragma unroll
        for (int j = 0; j < 4; ++j) {
            int nl = ty * 4 + j;
            dst[(size_t)(n0 + nl) * K + k0 + tx] = f2bf(S.Ts[tx][nl]);
        }
    }
}

// ------------------------------------------------------- bf16 MFMA GEMM
// bf16 output path repacks the tile through LDS -> uint4 stores.
#define LDSW 72
#define TILEC 132
template<typename CT>
__global__ __launch_bounds__(256) void gemm_bf16(const ushort* __restrict__ A,
                                                 const ushort* __restrict__ Bt,
                                                 CT* __restrict__ C,
                                                 int M, int N, int K, int nx) {
    __shared__ ushort LB[2 * 128 * LDSW];
    ushort* As = LB;
    ushort* Bs = LB + 128 * LDSW;
    const int tid  = threadIdx.x;
    const int nwg  = gridDim.x;
    const int work = (blockIdx.x & 7) * (nwg >> 3) + (blockIdx.x >> 3);
    const int m0 = (work / nx) * 128, n0 = (work % nx) * 128;
    const int wid = tid >> 6, lane = tid & 63;
    const int wr = wid >> 1, wc = wid & 1;
    const int r = tid >> 1, kq = tid & 1;
    const int fr = lane & 15, kc = lane >> 4;

    f32x4 acc[4][4];
    #pragma unroll
    for (int i = 0; i < 4; ++i)
        #pragma unroll
        for (int j = 0; j < 4; ++j) acc[i][j] = (f32x4)0.f;

    for (int kt = 0; kt < K; kt += 64) {
        const ushort* ap = &A [(size_t)(m0 + r) * K + kt + kq * 32];
        const ushort* bp = &Bt[(size_t)(n0 + r) * K + kt + kq * 32];
        #pragma unroll
        for (int v = 0; v < 4; ++v) {
            *(uint4*)&As[r * LDSW + kq * 32 + v * 8] = *(const uint4*)(ap + v * 8);
            *(uint4*)&Bs[r * LDSW + kq * 32 + v * 8] = *(const uint4*)(bp + v * 8);
        }
        __syncthreads();
        #pragma unroll
        for (int kk = 0; kk < 2; ++kk) {
            bf16x8 af[4], bfv[4];
            #pragma unroll
            for (int i = 0; i < 4; ++i) {
                af[i]  = *(const bf16x8*)&As[(wr * 64 + i * 16 + fr) * LDSW + kk * 32 + kc * 8];
                bfv[i] = *(const bf16x8*)&Bs[(wc * 64 + i * 16 + fr) * LDSW + kk * 32 + kc * 8];
            }
            #pragma unroll
            for (int i = 0; i < 4; ++i)
                #pragma unroll
                for (int j = 0; j < 4; ++j)
                    acc[i][j] = __builtin_amdgcn_mfma_f32_16x16x32_bf16(af[i], bfv[j], acc[i][j], 0, 0, 0);
        }
        __syncthreads();
    }
    if constexpr (sizeof(CT) == 4) {
        #pragma unroll
        for (int i = 0; i < 4; ++i)
            #pragma unroll
            for (int j = 0; j < 4; ++j)
                #pragma unroll
                for (int q = 0; q < 4; ++q) {
                    int rr = m0 + wr * 64 + i * 16 + (lane >> 4) * 4 + q;
                    int cc = n0 + wc * 64 + j * 16 + (lane & 15);
                    C[(size_t)rr * N + cc] = acc[i][j][q];
                }
    } else {
        // repack via LDS (As/Bs dead), then vectorized uint4 stores
        ushort (*Tile)[TILEC] = (ushort (*)[TILEC])LB;
        #pragma unroll
        for (int i = 0; i < 4; ++i)
            #pragma unroll
            for (int j = 0; j < 4; ++j)
                #pragma unroll
                for (int q = 0; q < 4; ++q)
                    Tile[wr * 64 + i * 16 + (lane >> 4) * 4 + q]
                        [wc * 64 + j * 16 + (lane & 15)] = f2bf(acc[i][j][q]);
        __syncthreads();
        #pragma unroll
        for (int it = 0; it < 8; ++it) {
            int idx = tid + it * 256;        // 2048 grains: 128 rows x 16
            int rr = idx >> 4, g = idx & 15;
            *(uint4*)&C[(size_t)(m0 + rr) * N + n0 + g * 8] = *(uint4*)&Tile[rr][g * 8];
        }
    }
}

// ------------------- depthwise conv + SiLU: LDS weights, 4 t-steps/thread
__global__ __launch_bounds__(256) void conv_silu_k(const ushort* __restrict__ zx,
                                                   const float* __restrict__ cw,
                                                   const float* __restrict__ cb,
                                                   ushort* __restrict__ out) {
    __shared__ float cws[KCONV][CONVDIM];
    __shared__ float cbs[CONVDIM];
    const int tid = threadIdx.x;
    #pragma unroll
    for (int it = 0; it < 3; ++it) {
        int i = tid + it * 256;
        cbs[i] = cb[i];
        #pragma unroll
        for (int k = 0; k < KCONV; ++k) cws[k][i] = cw[i * KCONV + k];
    }
    __syncthreads();

    const int idx = blockIdx.x * 256 + tid;
    const int cg = idx % 96, btq = idx / 96;
    const int c0 = cg * 8;
    const int bt0 = btq * 4;
    const int t0 = bt0 & (SEQ - 1);

    float wv[KCONV][8], bias[8];
    #pragma unroll
    for (int j = 0; j < 8; ++j) bias[j] = cbs[c0 + j];
    #pragma unroll
    for (int k = 0; k < KCONV; ++k) {
        float4 a = *(const float4*)&cws[k][c0];
        float4 b = *(const float4*)&cws[k][c0 + 4];
        wv[k][0] = a.x; wv[k][1] = a.y; wv[k][2] = a.z; wv[k][3] = a.w;
        wv[k][4] = b.x; wv[k][5] = b.y; wv[k][6] = b.z; wv[k][7] = b.w;
    }
    float xr[7][8];
    #pragma unroll
    for (int r = 0; r < 7; ++r) {
        int tt = t0 - 3 + r;
        if (tt >= 0) {
            uint4 v = *(const uint4*)&zx[(size_t)(bt0 - 3 + r) * ZXLD + DINNER + c0];
            const ushort* pv = (const ushort*)&v;
            #pragma unroll
            for (int j = 0; j < 8; ++j) xr[r][j] = bf2f(pv[j]);
        } else {
            #pragma unroll
            for (int j = 0; j < 8; ++j) xr[r][j] = 0.f;
        }
    }
    #pragma unroll
    for (int dt = 0; dt < 4; ++dt) {
        float acc[8];
        #pragma unroll
        for (int j = 0; j < 8; ++j) acc[j] = bias[j];
        #pragma unroll
        for (int k = 0; k < KCONV; ++k)
            #pragma unroll
            for (int j = 0; j < 8; ++j) acc[j] += xr[dt + k][j] * wv[k][j];
        ushort res[8];
        #pragma unroll
        for (int j = 0; j < 8; ++j)
            res[j] = f2bf(acc[j] / (1.f + __expf(-acc[j])));
        *(uint4*)&out[(size_t)(bt0 + dt) * CONVDIM + c0] = *(uint4*)res;
    }
}

// -------------------------------------------------- SSD MFMA kernel (XCD-swizzled)
#define SLDA 136
#define SLDB 72
__global__ __launch_bounds__(256) void ssd_mfma_k(const ushort* __restrict__ xbc,
                                                  const float* __restrict__ dtb,
                                                  const float* __restrict__ adtb,
                                                  const float* __restrict__ Dp,
                                                  ushort* __restrict__ ybuf,
                                                  ushort* __restrict__ states,
                                                  float* __restrict__ acsbuf,
                                                  float* __restrict__ chunksum) {
    const int wk = (blockIdx.x & 7) * 64 + (blockIdx.x >> 3);
    const int hgrp = wk & 1, c = (wk >> 1) & 15, b = wk >> 5;
    const int row0 = b * SEQ + c * LCHUNK;
    const int tid = threadIdx.x;
    const int lane = tid & 63, w = tid >> 6;
    const int fr = lane & 15, kc = lane >> 4;

    __shared__ union {
        struct { ushort Bs[64][SLDA]; ushort Cs[64][SLDA]; } p1;
        struct { ushort Ps[64][SLDB]; ushort Xt[64][SLDB]; ushort Xdt[64][SLDB]; } p2;
    } U;
    __shared__ ushort Btr[128][SLDB];
    __shared__ float acs4[4][64];
    __shared__ float dts[4][64];
    __shared__ float decs[4][64];

    {
        const int hh = hgrp * 4 + w;
        float v = adtb[(size_t)(row0 + lane) * NHEADS + hh];
        #pragma unroll
        for (int off = 1; off < 64; off <<= 1) {
            float t = __shfl_up(v, off);
            if (lane >= off) v += t;
        }
        acs4[w][lane] = v;
        float tot = __shfl(v, 63);
        decs[w][lane] = __expf(tot - v);
        acsbuf[(((size_t)b * NCHUNK + c) * NHEADS + hh) * LCHUNK + lane] = v;
        if (lane == 63) chunksum[((size_t)b * NCHUNK + c) * NHEADS + hh] = v;
        dts[w][lane] = dtb[(size_t)(row0 + lane) * NHEADS + hh];
    }
    for (int it = 0; it < 4; ++it) {
        int idx = tid + it * 256;
        int l = idx >> 4, ng = idx & 15;
        const ushort* rp = &xbc[(size_t)(row0 + l) * CONVDIM + DINNER];
        uint4 vb = *(const uint4*)(rp + ng * 8);
        *(uint4*)&U.p1.Bs[l][ng * 8] = vb;
        uint4 vc = *(const uint4*)(rp + DSTATE + ng * 8);
        *(uint4*)&U.p1.Cs[l][ng * 8] = vc;
        const ushort* pv = (const ushort*)&vb;
        #pragma unroll
        for (int j = 0; j < 8; ++j) Btr[ng * 8 + j][l] = pv[j];
    }
    __syncthreads();

    const int wr = w >> 1, wc = w & 1;
    f32x4 accG[2][2];
    #pragma unroll
    for (int i = 0; i < 2; ++i)
        #pragma unroll
        for (int j = 0; j < 2; ++j) accG[i][j] = (f32x4)0.f;
    #pragma unroll
    for (int kt = 0; kt < 4; ++kt) {
        bf16x8 af[2], bfv[2];
        #pragma unroll
        for (int i = 0; i < 2; ++i) af[i]  = *(const bf16x8*)&U.p1.Cs[wr*32 + i*16 + fr][kt*32 + kc*8];
        #pragma unroll
        for (int j = 0; j < 2; ++j) bfv[j] = *(const bf16x8*)&U.p1.Bs[wc*32 + j*16 + fr][kt*32 + kc*8];
        #pragma unroll
        for (int i = 0; i < 2; ++i)
            #pragma unroll
            for (int j = 0; j < 2; ++j)
                accG[i][j] = __builtin_amdgcn_mfma_f32_16x16x32_bf16(af[i], bfv[j], accG[i][j], 0, 0, 0);
    }
    __syncthreads();

    for (int hl = 0; hl < 4; ++hl) {
        const int hh = hgrp * 4 + hl;
        {
            const int p = lane;
            ushort xt[16], xdt[16];
            #pragma unroll
            for (int j = 0; j < 16; ++j) {
                int l = w * 16 + j;
                float xv = bf2f(xbc[(size_t)(row0 + l) * CONVDIM + hh * HEADDIM + p])
                           * dts[hl][l];
                xt[j]  = f2bf(xv);
                xdt[j] = f2bf(xv * decs[hl][l]);
            }
            #pragma unroll
            for (int v = 0; v < 4; ++v) {
                *(ushort4*)&U.p2.Xt [p][w*16 + v*4] = *(ushort4*)&xt[v*4];
                *(ushort4*)&U.p2.Xdt[p][w*16 + v*4] = *(ushort4*)&xdt[v*4];
            }
        }
        #pragma unroll
        for (int i = 0; i < 2; ++i)
            #pragma unroll
            for (int j = 0; j < 2; ++j)
                #pragma unroll
                for (int q = 0; q < 4; ++q) {
                    int l = wr*32 + i*16 + (lane >> 4)*4 + q;
                    int s = wc*32 + j*16 + fr;
                    float v = 0.f;
                    if (s < l)       v = accG[i][j][q] * __expf(acs4[hl][l] - acs4[hl][s]);
                    else if (s == l) v = accG[i][j][q] + Dp[hh] / dts[hl][l];
                    U.p2.Ps[l][s] = f2bf(v);
                }
        __syncthreads();
        {
            f32x4 acc[4];
            #pragma unroll
            for (int j = 0; j < 4; ++j) acc[j] = (f32x4)0.f;
            #pragma unroll
            for (int kt = 0; kt < 2; ++kt) {
                bf16x8 af = *(const bf16x8*)&U.p2.Ps[w*16 + fr][kt*32 + kc*8];
                #pragma unroll
                for (int j = 0; j < 4; ++j) {
                    bf16x8 bfv = *(const bf16x8*)&U.p2.Xt[j*16 + fr][kt*32 + kc*8];
                    acc[j] = __builtin_amdgcn_mfma_f32_16x16x32_bf16(af, bfv, acc[j], 0, 0, 0);
                }
            }
            #pragma unroll
            for (int j = 0; j < 4; ++j)
                #pragma unroll
                for (int q = 0; q < 4; ++q) {
                    int l = w*16 + (lane >> 4)*4 + q;
                    int p = j*16 + fr;
                    ybuf[(size_t)(row0 + l) * DINNER + hh * HEADDIM + p] = f2bf(acc[j][q]);
                }
        }
        {
            f32x4 acc2[4][2];
            #pragma unroll
            for (int mt = 0; mt < 4; ++mt)
                #pragma unroll
                for (int jt = 0; jt < 2; ++jt) acc2[mt][jt] = (f32x4)0.f;
            #pragma unroll
            for (int kt = 0; kt < 2; ++kt) {
                bf16x8 a4[4], b2[2];
                #pragma unroll
                for (int mt = 0; mt < 4; ++mt) a4[mt] = *(const bf16x8*)&U.p2.Xdt[mt*16 + fr][kt*32 + kc*8];
                #pragma unroll
                for (int jt = 0; jt < 2; ++jt) b2[jt] = *(const bf16x8*)&Btr[w*32 + jt*16 + fr][kt*32 + kc*8];
                #pragma unroll
                for (int mt = 0; mt < 4; ++mt)
                    #pragma unroll
                    for (int jt = 0; jt < 2; ++jt)
                        acc2[mt][jt] = __builtin_amdgcn_mfma_f32_16x16x32_bf16(a4[mt], b2[jt], acc2[mt][jt], 0, 0, 0);
            }
            ushort* sb = states + ((((size_t)b * NCHUNK + c) * NHEADS + hh) * HEADDIM) * DSTATE;
            #pragma unroll
            for (int mt = 0; mt < 4; ++mt)
                #pragma unroll
                for (int jt = 0; jt < 2; ++jt)
                    #pragma unroll
                    for (int q = 0; q < 4; ++q) {
                        int p = mt*16 + (lane >> 4)*4 + q;
                        int n = w*32 + jt*16 + fr;
                        sb[(size_t)p * DSTATE + n] = f2bf(acc2[mt][jt][q]);
                    }
        }
        __syncthreads();
    }
}

// ------------------------------------- inter-chunk scan (bf16 states, f32 regs)
__global__ __launch_bounds__(256) void scan_k(ushort* __restrict__ states,
                                              const float* __restrict__ chunksum) {
    const int bid = blockIdx.x;
    const int pq = bid & 3, h = (bid >> 2) & 7, b = bid >> 5;
    const int tid = threadIdx.x;
    float pref[8];
    #pragma unroll
    for (int k = 0; k < 8; ++k) pref[k] = 0.f;
    for (int c = 0; c < NCHUNK; ++c) {
        ushort* base = states + (((size_t)b * NCHUNK + c) * NHEADS + h) * (HEADDIM * DSTATE)
                       + pq * 2048 + tid * 8;
        float dec = __expf(chunksum[((size_t)b * NCHUNK + c) * NHEADS + h]);
        uint4 v = *(const uint4*)base;
        const ushort* pv = (const ushort*)&v;
        ushort outv[8];
        #pragma unroll
        for (int j = 0; j < 8; ++j) {
            float cur = bf2f(pv[j]);
            outv[j] = f2bf(pref[j]);
            pref[j] = dec * pref[j] + cur;
        }
        *(uint4*)base = *(uint4*)outv;
    }
}

// ----- Y_off + gate + RMSNorm, 32-row blocks (512 blocks, XCD-chunked)
__global__ __launch_bounds__(256) void yoff_gate_k(const ushort* __restrict__ xbc,
                                                   const ushort* __restrict__ states,
                                                   const float* __restrict__ acsbuf,
                                                   const ushort* __restrict__ ybuf,
                                                   const ushort* __restrict__ zx,
                                                   const float* __restrict__ nw,
                                                   ushort* __restrict__ gbuf) {
    const int wk = (blockIdx.x & 7) * 64 + (blockIdx.x >> 3);
    const int half = wk & 1, c = (wk >> 1) & 15, b = wk >> 5;
    const int row0 = b * SEQ + c * LCHUNK + half * 32;
    const int tid = threadIdx.x;
    const int lane = tid & 63, w = tid >> 6;
    const int fr = lane & 15, kc = lane >> 4;
    const int rw = (w & 1) * 16;           // wave row range (16 of 32)
    const int j0 = (w >> 1) * 2;           // wave col-frag pair
    __shared__ ushort Csh[32][SLDA];
    __shared__ ushort Ssh[64][SLDA];
    __shared__ ushort Ys[32][520];
    __shared__ float eah[32];

    #pragma unroll
    for (int it = 0; it < 2; ++it) {
        int idx = tid + it * 256;          // 512 grains: l(32) x ng(16)
        int l = idx >> 4, ng = idx & 15;
        *(uint4*)&Csh[l][ng * 8] =
            *(const uint4*)&xbc[(size_t)(row0 + l) * CONVDIM + DINNER + DSTATE + ng * 8];
    }
    for (int hl = 0; hl < NHEADS; ++hl) {
        __syncthreads();
        const ushort* sb = states + ((((size_t)b * NCHUNK + c) * NHEADS + hl) * HEADDIM) * DSTATE;
        #pragma unroll
        for (int it = 0; it < 4; ++it) {
            int idx = tid + it * 256;
            int p = idx >> 4, ng = idx & 15;
            *(uint4*)&Ssh[p][ng * 8] = *(const uint4*)&sb[(size_t)p * DSTATE + ng * 8];
        }
        if (tid < 32)
            eah[tid] = __expf(acsbuf[(((size_t)b * NCHUNK + c) * NHEADS + hl) * LCHUNK
                                     + half * 32 + tid]);
        __syncthreads();
        f32x4 acc[2];
        acc[0] = (f32x4)0.f; acc[1] = (f32x4)0.f;
        #pragma unroll
        for (int kt = 0; kt < 4; ++kt) {
            bf16x8 af = *(const bf16x8*)&Csh[rw + fr][kt*32 + kc*8];
            #pragma unroll
            for (int jj = 0; jj < 2; ++jj) {
                bf16x8 bfv = *(const bf16x8*)&Ssh[(j0+jj)*16 + fr][kt*32 + kc*8];
                acc[jj] = __builtin_amdgcn_mfma_f32_16x16x32_bf16(af, bfv, acc[jj], 0, 0, 0);
            }
        }
        #pragma unroll
        for (int jj = 0; jj < 2; ++jj)
            #pragma unroll
            for (int q = 0; q < 4; ++q) {
                int l = rw + (lane >> 4)*4 + q;
                int p = (j0+jj)*16 + fr;
                float val = bf2f(ybuf[(size_t)(row0 + l) * DINNER + hl * HEADDIM + p])
                            + acc[jj][q] * eah[l];
                Ys[l][hl * HEADDIM + p] = f2bf(val);
            }
    }
    __syncthreads();
    float nwv[8];
    #pragma unroll
    for (int j = 0; j < 8; ++j) nwv[j] = nw[lane * 8 + j];
    #pragma unroll
    for (int i = 0; i < 8; ++i) {
        int l = w * 8 + i;
        int row = row0 + l;
        uint4 zv = *(const uint4*)&zx[(size_t)row * ZXLD + lane * 8];
        const ushort* pz = (const ushort*)&zv;
        float g[8], ss = 0.f;
        #pragma unroll
        for (int j = 0; j < 8; ++j) {
            float y = bf2f(Ys[l][lane * 8 + j]);
            float z = bf2f(pz[j]);
            float sz = z / (1.f + __expf(-z));
            g[j] = y * sz;
            ss += g[j] * g[j];
        }
        #pragma unroll
        for (int off = 32; off; off >>= 1) ss += __shfl_xor(ss, off);
        float r = rsqrtf(ss / (float)DINNER + EPSV);
        ushort res[8];
        #pragma unroll
        for (int j = 0; j < 8; ++j) res[j] = f2bf(g[j] * r * nwv[j]);
        *(uint4*)&gbuf[(size_t)row * DINNER + lane * 8] = *(uint4*)res;
    }
}

// ---------------------------------------------------------------- launch
extern "C" void kernel_launch(void* const* d_in, const int* in_sizes, int n_in,
                              void* d_out, int out_size, void* d_ws, size_t ws_size,
                              hipStream_t stream) {
    const float* u       = (const float*)d_in[0];
    const float* W_in    = (const float*)d_in[1];
    const float* conv_w  = (const float*)d_in[2];
    const float* conv_b  = (const float*)d_in[3];
    const float* dt_bias = (const float*)d_in[4];
    const float* A_log   = (const float*)d_in[5];
    const float* Dp      = (const float*)d_in[6];
    const float* norm_w  = (const float*)d_in[7];
    const float* W_out   = (const float*)d_in[8];
    float* out = (float*)d_out;

    char* p = (char*)d_ws;
    ushort* zx       = (ushort*)p; p += (size_t)ROWS * ZXLD * sizeof(ushort);
    ushort* ybuf     = (ushort*)p; p += (size_t)ROWS * DINNER * sizeof(ushort);
    ushort* gbuf     = (ushort*)p; p += (size_t)ROWS * DINNER * sizeof(ushort);
    ushort* states   = (ushort*)p; p += (size_t)BATCHN * NCHUNK * NHEADS * HEADDIM * DSTATE * sizeof(ushort);
    ushort* xbc      = (ushort*)p; p += (size_t)ROWS * CONVDIM * sizeof(ushort);
    ushort* ubf      = (ushort*)p; p += (size_t)ROWS * DMODEL * sizeof(ushort);
    float*  dtb      = (float*)p;  p += (size_t)ROWS * NHEADS  * sizeof(float);
    float*  adtb     = (float*)p;  p += (size_t)ROWS * NHEADS  * sizeof(float);
    float*  chunksum = (float*)p;  p += (size_t)BATCHN * NCHUNK * NHEADS * sizeof(float);
    float*  acsbuf   = (float*)p;  p += (size_t)BATCHN * NCHUNK * NHEADS * LCHUNK * sizeof(float);
    ushort* WtA      = (ushort*)p; p += (size_t)ZXLD * DMODEL * sizeof(ushort);
    ushort* WtB      = (ushort*)p; p += (size_t)DMODEL * DINNER * sizeof(ushort);

    prep_k<<<960, 256, 0, stream>>>(u, W_in, W_out, dt_bias, A_log,
                                    ubf, dtb, adtb, WtA, WtB);
    gemm_bf16<ushort><<<(ZXLD/128)*(ROWS/128), 256, 0, stream>>>(
        ubf, WtA, zx, ROWS, ZXLD, DMODEL, ZXLD/128);
    conv_silu_k<<<(ROWS/4)*96/256, 256, 0, stream>>>(zx, conv_w, conv_b, xbc);
    ssd_mfma_k<<<512, 256, 0, stream>>>(
        xbc, dtb, adtb, Dp, ybuf, states, acsbuf, chunksum);
    scan_k<<<BATCHN*NHEADS*4, 256, 0, stream>>>(states, chunksum);
    yoff_gate_k<<<512, 256, 0, stream>>>(
        xbc, states, acsbuf, ybuf, zx, norm_w, gbuf);
    gemm_bf16<float><<<(DMODEL/128)*(ROWS/128), 256, 0, stream>>>(
        gbuf, WtB, out, ROWS, DMODEL, DINNER, DMODEL/128);
}